// Round 5
// baseline (781.281 us; speedup 1.0000x reference)
//
#include <hip/hip_runtime.h>
#include <hip/hip_bf16.h>
#include <math.h>

namespace {
constexpr int kB  = 128;
constexpr int kC  = 321;
constexpr int kN0 = 720;
constexpr int kCp = 384;   // padded channel dim for MFMA
}

typedef __attribute__((ext_vector_type(8))) short short8;
typedef __attribute__((ext_vector_type(4))) float floatx4;
typedef __attribute__((ext_vector_type(16))) float floatx16;

__device__ __forceinline__ floatx16 mfma32(short8 a, short8 b, floatx16 c) {
  return __builtin_amdgcn_mfma_f32_32x32x16_bf16(a, b, c, 0, 0, 0);
}

// db6 analysis filters (H0 = lowpass, H1 = qmf highpass), and reversed copies
__constant__ float c_h0[12] = {
  0.11154074335008017f, 0.4946238903983854f, 0.7511339080215775f,
  0.3152503517092432f, -0.22626469396516913f, -0.12976686756709563f,
  0.09750160558707936f, 0.02752286553001629f, -0.031582039318031156f,
  0.0005538422009938016f, 0.004777257511010651f, -0.00107730108499558f};
__constant__ float c_h1[12] = {
  -0.00107730108499558f, -0.004777257511010651f, 0.0005538422009938016f,
  0.031582039318031156f, 0.02752286553001629f, -0.09750160558707936f,
  -0.12976686756709563f, 0.22626469396516913f, 0.3152503517092432f,
  -0.7511339080215775f, 0.4946238903983854f, -0.11154074335008017f};
__constant__ float c_h0r[12] = {
  -0.00107730108499558f, 0.004777257511010651f, 0.0005538422009938016f,
  -0.031582039318031156f, 0.02752286553001629f, 0.09750160558707936f,
  -0.12976686756709563f, -0.22626469396516913f, 0.3152503517092432f,
  0.7511339080215775f, 0.4946238903983854f, 0.11154074335008017f};
__constant__ float c_h1r[12] = {
  -0.11154074335008017f, 0.4946238903983854f, -0.7511339080215775f,
  0.3152503517092432f, 0.22626469396516913f, -0.12976686756709563f,
  -0.09750160558707936f, 0.02752286553001629f, 0.031582039318031156f,
  0.0005538422009938016f, -0.004777257511010651f, -0.00107730108499558f};

__device__ __forceinline__ float fast_tanh(float x) {
  float e = __expf(2.f * x);
  return 1.f - 2.f / (e + 1.f);
}
__device__ __forceinline__ unsigned short f2b(float f) {
  __hip_bfloat16 h = __float2bfloat16(f);
  return __builtin_bit_cast(unsigned short, h);
}

// async global->LDS, 16B per lane; LDS dest = wave-uniform base + lane*16
__device__ __forceinline__ void gload16(const unsigned short* g, short* l) {
  __builtin_amdgcn_global_load_lds(
      (const __attribute__((address_space(1))) unsigned int*)g,
      (__attribute__((address_space(3))) unsigned int*)l, 16, 0, 0);
}

// ---------- mean/std over time axis: 8 chunks x 90 t, unrolled for MLP ----------
__global__ void __launch_bounds__(128) partial_ms_kernel(
    const float* __restrict__ x, float* __restrict__ ps, float* __restrict__ ps2) {
  int b = blockIdx.x, chunk = blockIdx.y;
  int c = blockIdx.z * 128 + threadIdx.x;
  if (c >= kC) return;
  const float* xb = x + (size_t)b * kN0 * kC + c;
  int t0 = chunk * 90;
  float s = 0.f, s2 = 0.f;
#pragma unroll 15
  for (int i = 0; i < 90; ++i) {
    float v = xb[(size_t)(t0 + i) * kC];
    s += v; s2 += v * v;
  }
  ps [(b * 8 + chunk) * kC + c] = s;
  ps2[(b * 8 + chunk) * kC + c] = s2;
}

__global__ void __launch_bounds__(256) finalize_ms_kernel(
    const float* __restrict__ ps, const float* __restrict__ ps2,
    float* __restrict__ mout, float* __restrict__ sout,
    float* __restrict__ meanw, float* __restrict__ invw) {
  int i = blockIdx.x * 256 + threadIdx.x;
  if (i >= kB * kC) return;
  int b = i / kC, c = i - b * kC;
  float s = 0.f, s2 = 0.f;
#pragma unroll
  for (int k = 0; k < 8; ++k) { s += ps[(b * 8 + k) * kC + c]; s2 += ps2[(b * 8 + k) * kC + c]; }
  float mean = s * (1.f / (float)kN0);
  float var = s2 * (1.f / (float)kN0) - mean * mean;
  float sd = sqrtf(var + 1e-5f);
  mout[i] = mean; sout[i] = sd;
  meanw[i] = mean; invw[i] = 1.f / sd;
}

__device__ __forceinline__ int sym_reflect(int t, int N) {
  t = (t < 0) ? (-1 - t) : t;
  t = (t >= N) ? (2 * N - 1 - t) : t;
  return t;
}

// ---------- fused tiled DWT level ----------
template <bool NORM, bool LO_F32, bool LO_BF16>
__global__ void __launch_bounds__(256) dwt_fused_kernel(
    const float* __restrict__ in, const float* __restrict__ meanw,
    const float* __restrict__ invw, float* __restrict__ loF,
    unsigned short* __restrict__ loB, unsigned short* __restrict__ hiB,
    int N, int L, int Lp) {
  __shared__ float xs[138][64];
  __shared__ unsigned short los[64][72];
  __shared__ unsigned short his[64][72];
  const int b = blockIdx.z;
  const int n0 = blockIdx.x * 64, c0 = blockIdx.y * 64;
  const int tid = threadIdx.x;
  const int cl = tid & 63, wv = tid >> 6;
  const int c = c0 + cl;
  const int t0 = 2 * n0 - 10;
  const float* ib = in + (size_t)b * N * kC;
  float mean = 0.f, inv = 1.f;
  if (NORM && c < kC) { mean = meanw[b * kC + c]; inv = invw[b * kC + c]; }
  for (int r = wv; r < 138; r += 4) {
    int t = sym_reflect(t0 + r, N);
    float v = (c < kC) ? ib[(size_t)t * kC + c] : 0.f;
    if (NORM) v = (v - mean) * inv;
    xs[r][cl] = v;
  }
  __syncthreads();
#pragma unroll 4
  for (int k = 0; k < 16; ++k) {
    int nl = wv + 4 * k;
    int n = n0 + nl;
    float a0 = 0.f, a1 = 0.f;
    int base = 2 * nl;
#pragma unroll
    for (int j = 0; j < 12; ++j) {
      float v = xs[base + j][cl];
      a0 += v * c_h0[j]; a1 += v * c_h1[j];
    }
    bool valid = (n < L) && (c < kC);
    if (LO_F32 && valid) loF[((size_t)b * L + n) * kC + c] = a0;
    if (LO_BF16) los[cl][nl] = f2b(valid ? a0 : 0.f);
    his[cl][nl] = f2b(valid ? a1 : 0.f);
  }
  __syncthreads();
  int row = tid >> 2, part = tid & 3;
  size_t dst = ((size_t)b * kCp + c0 + row) * Lp + n0 + part * 16;
  *(uint4*)(hiB + dst)     = *(const uint4*)&his[row][part * 16];
  *(uint4*)(hiB + dst + 8) = *(const uint4*)&his[row][part * 16 + 8];
  if (LO_BF16) {
    *(uint4*)(loB + dst)     = *(const uint4*)&los[row][part * 16];
    *(uint4*)(loB + dst + 8) = *(const uint4*)&los[row][part * 16 + 8];
  }
}

// ---------- all-level weight fp32 [L][L] -> bf16 [Lp][Lp] zero-padded ----------
struct WcArgs { const float* src[8]; unsigned short* dst[8]; int L[8]; int Lp[8]; };
__global__ void __launch_bounds__(256) wconv_all_kernel(WcArgs a) {
  int lvl = blockIdx.y;
  int Lp = a.Lp[lvl], L = a.L[lvl];
  int i = blockIdx.x * 256 + threadIdx.x;
  if (i >= Lp * Lp) return;
  int p = i / Lp, l = i - p * Lp;
  a.dst[lvl][i] = f2b((p < L && l < L) ? a.src[lvl][(size_t)p * L + l] : 0.f);
}

// ---------- ALL levels Q+K projections fused; 32x32x16 MFMA; K-step 32;
// triple-buffered 2-deep counted-vmcnt pipeline (loads never drain to 0 in
// steady state). Block 512 thr = 8 waves (4p x 2c), tile 128p x 128c, both
// Q and K outputs (X staged once). LDS rows are 64 B with 16B-chunk XOR
// swizzle phys = logical ^ (row&3): inverse-permuted gload source, linear
// LDS dest, per-lane-constant read chunk -> 8 dwords/bank (balanced).
// Epilogue: padded LDS bounce -> uint4 coalesced stores. ----------
struct QKAllArgs {
  const unsigned short* W[8];     // [2*lvl+sel]
  const unsigned short* Xt[4];
  const float* bias[8];
  unsigned short* Y[8];
  int Lp[4], L[4], yOff[4];       // yOff = {0,1,4,6} (p-tiles per level: 1,3,2,1)
};
__global__ void __launch_bounds__(512, 4) qk_all_kernel(QKAllArgs a) {
  const int y = blockIdx.y;
  const int lvl = (y >= a.yOff[1]) + (y >= a.yOff[2]) + (y >= a.yOff[3]);
  const int Lp = a.Lp[lvl], L = a.L[lvl];
  const int pBase = (y - a.yOff[lvl]) * 128;
  const unsigned short* W0 = a.W[2 * lvl]     + (size_t)pBase * Lp;
  const unsigned short* W1 = a.W[2 * lvl + 1] + (size_t)pBase * Lp;
  const int b = blockIdx.z;
  const int cBase = blockIdx.x * 128;
  const int tid = threadIdx.x;
  const int ln = tid & 63, w = tid >> 6;
  const int wm = w & 3, wn = w >> 2;        // 4 p-waves x 2 c-waves
  __shared__ __align__(16) short smem[3 * 384 * 32];   // 72 KB: 3 phases x (Aq128|Ak128|X128) x 32
  floatx16 accQ[2] = {}, accK[2] = {};      // [c-frag], 64 VGPR
  const unsigned short* Xb = a.Xt[lvl] + ((size_t)b * kCp + cBase) * Lp;
  // staging: 24 gload16/phase, 3 per wave; lane -> row o*16+(ln>>2),
  // phys chunk ln&3, source logical chunk = (ln&3) ^ (row&3)
  const int lr = ln >> 2;
  const int srcC = ((ln & 3) ^ (lr & 3)) * 8;
  const unsigned short* srcs[3];
#pragma unroll
  for (int i = 0; i < 3; ++i) {
    int o = w * 3 + i;          // 0..23
    int rr = o * 16 + lr;
    const unsigned short* s = (o < 8)  ? (W0 + (size_t)rr * Lp)
                            : (o < 16) ? (W1 + (size_t)(rr - 128) * Lp)
                                       : (Xb + (size_t)(rr - 256) * Lp);
    srcs[i] = s + srcC;
  }
  auto stage = [&](int buf, int lc) {
#pragma unroll
    for (int i = 0; i < 3; ++i)
      gload16(srcs[i] + lc, &smem[buf * 12288 + (w * 3 + i) * 512]);
  };
  // fragment read geometry (A: row=ln&31, k-group=(ln>>5)*8; same for B)
  const int rl = ln & 31, sel = ln >> 5, sw = ln & 3;
  const int kc0 = ((sel) ^ sw) * 8;         // k-sub 0 phys chunk
  const int kc1 = ((2 + sel) ^ sw) * 8;     // k-sub 1 phys chunk
  const int aOff  = (wm * 32 + rl) * 32;
  const int akOff = 4096 + aOff;
  const int bOff0 = 8192 + (wn * 64 + rl) * 32;
  const int bOff1 = bOff0 + 1024;           // +32 rows
  const int nt = Lp >> 5;
  stage(0, 0);
  stage(1, 32);
  int bufn = 2, lc = 64, bc = 0;
  for (int kt = 0; kt < nt; ++kt) {
    if (kt + 1 < nt) asm volatile("s_waitcnt vmcnt(3)" ::: "memory");
    else             asm volatile("s_waitcnt vmcnt(0)" ::: "memory");
    __builtin_amdgcn_s_barrier();
    __builtin_amdgcn_sched_barrier(0);
    if (kt + 2 < nt) {
      stage(bufn, lc);
      lc += 32;
      bufn = (bufn == 2) ? 0 : bufn + 1;
    }
    const int ph = bc * 12288;
    short8 a0 = *(const short8*)&smem[ph + aOff + kc0];
    short8 k0 = *(const short8*)&smem[ph + akOff + kc0];
    short8 b0 = *(const short8*)&smem[ph + bOff0 + kc0];
    short8 b1 = *(const short8*)&smem[ph + bOff1 + kc0];
    accQ[0] = mfma32(a0, b0, accQ[0]); accQ[1] = mfma32(a0, b1, accQ[1]);
    accK[0] = mfma32(k0, b0, accK[0]); accK[1] = mfma32(k0, b1, accK[1]);
    a0 = *(const short8*)&smem[ph + aOff + kc1];
    k0 = *(const short8*)&smem[ph + akOff + kc1];
    b0 = *(const short8*)&smem[ph + bOff0 + kc1];
    b1 = *(const short8*)&smem[ph + bOff1 + kc1];
    accQ[0] = mfma32(a0, b0, accQ[0]); accQ[1] = mfma32(a0, b1, accQ[1]);
    accK[0] = mfma32(k0, b0, accK[0]); accK[1] = mfma32(k0, b1, accK[1]);
    bc = (bc == 2) ? 0 : bc + 1;
  }
  __syncthreads();
  // epilogue: bounce [128p][136c-pad] (uint4-aligned rows), then coalesced stores.
  // Q zeroes pad rows p>=L; K zeroes pad cols c>=kC.
  short* bnc = smem;
  const int cl = wn * 64 + rl;
  const bool c0v = (cBase + cl) < kC, c1v = (cBase + cl + 32) < kC;
  {
    const float* bias = a.bias[2 * lvl];
#pragma unroll
    for (int reg = 0; reg < 16; ++reg) {
      int pl = wm * 32 + (reg & 3) + 8 * (reg >> 2) + 4 * sel;
      int p = pBase + pl;
      bool pv = p < L;
      float bq = pv ? bias[p] : 0.f;
      float v0 = fast_tanh(accQ[0][reg] + bq); if (!pv) v0 = 0.f;
      float v1 = fast_tanh(accQ[1][reg] + bq); if (!pv) v1 = 0.f;
      bnc[pl * 136 + cl]      = (short)f2b(v0);
      bnc[pl * 136 + cl + 32] = (short)f2b(v1);
    }
  }
  __syncthreads();
  {
    unsigned short* Yd = a.Y[2 * lvl];
#pragma unroll
    for (int j = 0; j < 4; ++j) {
      int idx = tid + j * 512;
      int row = idx >> 4, ch = idx & 15;
      *(uint4*)(Yd + ((size_t)b * Lp + pBase + row) * kCp + cBase + ch * 8) =
          *(const uint4*)&bnc[row * 136 + ch * 8];
    }
  }
  __syncthreads();
  {
    const float* bias = a.bias[2 * lvl + 1];
#pragma unroll
    for (int reg = 0; reg < 16; ++reg) {
      int pl = wm * 32 + (reg & 3) + 8 * (reg >> 2) + 4 * sel;
      int p = pBase + pl;
      bool pv = p < L;
      float bq = pv ? bias[p] : 0.f;
      float v0 = fast_tanh(accK[0][reg] + bq); if (!c0v) v0 = 0.f;
      float v1 = fast_tanh(accK[1][reg] + bq); if (!c1v) v1 = 0.f;
      bnc[pl * 136 + cl]      = (short)f2b(v0);
      bnc[pl * 136 + cl + 32] = (short)f2b(v1);
    }
  }
  __syncthreads();
  {
    unsigned short* Yd = a.Y[2 * lvl + 1];
#pragma unroll
    for (int j = 0; j < 4; ++j) {
      int idx = tid + j * 512;
      int row = idx >> 4, ch = idx & 15;
      *(uint4*)(Yd + ((size_t)b * Lp + pBase + row) * kCp + cBase + ch * 8) =
          *(const uint4*)&bnc[row * 136 + ch * 8];
    }
  }
}

// ---------- ALL levels scores; 32x32x16 MFMA; same tri-buffer pipeline.
// Block 256 thr = 4 waves (2l x 2s), tile 128l x 128s. XCD-swizzled 1D grid. ----------
struct ScAllArgs {
  const unsigned short* Q[4]; const unsigned short* K[4];
  float* wgt[4];
  int Lp[4], L[4], tOff[4];     // tOff = {0,1,10,14}
  float scale[4];
};
__global__ void __launch_bounds__(256, 4) scores_all_kernel(ScAllArgs a) {
  const int bid = blockIdx.x;                 // 0..1919
  const int wg = (bid & 7) * 240 + (bid >> 3);
  const int t = wg % 15;
  const int b = wg / 15;
  const int lvl = (t >= a.tOff[1]) + (t >= a.tOff[2]) + (t >= a.tOff[3]);
  const int rel = t - a.tOff[lvl];
  const int Lp = a.Lp[lvl], L = a.L[lvl];
  const int pt = Lp >> 7;
  const int sBase = (rel % pt) * 128;
  const int lBase = (rel / pt) * 128;
  const int tid = threadIdx.x;
  const int ln = tid & 63, w = tid >> 6;
  const int wm = w & 1, wn = w >> 1;          // 2 l-waves x 2 s-waves
  __shared__ __align__(16) short smem[3 * 256 * 32];   // 48 KB: 3 phases x (Q128|K128) x 32
  __shared__ float red[128];
  floatx16 acc[2][2] = {};                    // [l-frag][s-frag]
  const unsigned short* Qp = a.Q[lvl] + ((size_t)b * Lp + lBase) * kCp;
  const unsigned short* Kp = a.K[lvl] + ((size_t)b * Lp + sBase) * kCp;
  const int lr = ln >> 2;
  const int srcC = ((ln & 3) ^ (lr & 3)) * 8;
  const unsigned short* srcs[4];
#pragma unroll
  for (int i = 0; i < 4; ++i) {
    int o = w * 4 + i;          // 0..15
    int rr = o * 16 + lr;
    srcs[i] = ((o < 8) ? (Qp + (size_t)rr * kCp)
                       : (Kp + (size_t)(rr - 128) * kCp)) + srcC;
  }
  auto stage = [&](int buf, int cc) {
#pragma unroll
    for (int i = 0; i < 4; ++i)
      gload16(srcs[i] + cc, &smem[buf * 8192 + (w * 4 + i) * 512]);
  };
  const int rl = ln & 31, sel = ln >> 5, sw = ln & 3;
  const int kc0 = ((sel) ^ sw) * 8;
  const int kc1 = ((2 + sel) ^ sw) * 8;
  const int aOff0 = (wm * 64 + rl) * 32, aOff1 = aOff0 + 1024;
  const int bOff0 = 4096 + (wn * 64 + rl) * 32, bOff1 = bOff0 + 1024;
  if (tid < 128) red[tid] = 0.f;
  const int nt = kCp >> 5;   // 12
  stage(0, 0);
  stage(1, 32);
  int bufn = 2, cc = 64, bc = 0;
  for (int kt = 0; kt < nt; ++kt) {
    if (kt + 1 < nt) asm volatile("s_waitcnt vmcnt(4)" ::: "memory");
    else             asm volatile("s_waitcnt vmcnt(0)" ::: "memory");
    __builtin_amdgcn_s_barrier();
    __builtin_amdgcn_sched_barrier(0);
    if (kt + 2 < nt) {
      stage(bufn, cc);
      cc += 32;
      bufn = (bufn == 2) ? 0 : bufn + 1;
    }
    const int ph = bc * 8192;
    short8 a0 = *(const short8*)&smem[ph + aOff0 + kc0];
    short8 a1 = *(const short8*)&smem[ph + aOff1 + kc0];
    short8 b0 = *(const short8*)&smem[ph + bOff0 + kc0];
    short8 b1 = *(const short8*)&smem[ph + bOff1 + kc0];
    acc[0][0] = mfma32(a0, b0, acc[0][0]); acc[0][1] = mfma32(a0, b1, acc[0][1]);
    acc[1][0] = mfma32(a1, b0, acc[1][0]); acc[1][1] = mfma32(a1, b1, acc[1][1]);
    a0 = *(const short8*)&smem[ph + aOff0 + kc1];
    a1 = *(const short8*)&smem[ph + aOff1 + kc1];
    b0 = *(const short8*)&smem[ph + bOff0 + kc1];
    b1 = *(const short8*)&smem[ph + bOff1 + kc1];
    acc[0][0] = mfma32(a0, b0, acc[0][0]); acc[0][1] = mfma32(a0, b1, acc[0][1]);
    acc[1][0] = mfma32(a1, b0, acc[1][0]); acc[1][1] = mfma32(a1, b1, acc[1][1]);
    bc = (bc == 2) ? 0 : bc + 1;
  }
  const float scale = a.scale[lvl];
#pragma unroll
  for (int sf = 0; sf < 2; ++sf) {
    float p = 0.f;
#pragma unroll
    for (int lf = 0; lf < 2; ++lf)
#pragma unroll
      for (int reg = 0; reg < 16; ++reg)
        p += fast_tanh(acc[lf][sf][reg] * scale);
    p += __shfl_xor(p, 32);
    if (ln < 32) atomicAdd(&red[wn * 64 + sf * 32 + ln], p);
  }
  __syncthreads();
  if (tid < 128) {
    int s = sBase + tid;
    if (s < L) atomicAdd(&a.wgt[lvl][(size_t)b * L + s], red[tid]);
  }
}

// ---------- merged window mask + iw softmax (one launch) ----------
struct WinIwArgs {
  const float* wgt[4]; const float* al[4]; const float* be[4];
  float* mask[4]; int L[4];
  const float* iw[4]; float* sm[4]; int O[4];
};
__global__ void __launch_bounds__(64) winiw_kernel(WinIwArgs a) {
  int bx = blockIdx.x;
  int lane = threadIdx.x;
  if (bx < 512) {
    int lvl = bx >> 7, b = bx & 127;
    int L = a.L[lvl];
    const float* wgt = a.wgt[lvl] + (size_t)b * L;
    float al = a.al[lvl][0], be = a.be[lvl][0];
    float invL = 1.f / (float)L;
    int chunk = (L + 63) >> 6;            // <= 6
    int s0 = lane * chunk;
    float v[6];
    float csum = 0.f;
    for (int i = chunk - 1; i >= 0; --i) {
      int s = s0 + i;
      float xv = (s < L) ? wgt[s] * invL : 0.f;
      csum += xv; v[i] = csum;
    }
    float tot = csum;
    for (int o = 1; o < 64; o <<= 1) {
      float t = __shfl_down(tot, o);
      if (lane + o < 64) tot += t;
    }
    float excl = tot - csum;
    float m = -1e30f;
    for (int i = 0; i < chunk; ++i)
      if (s0 + i < L) m = fmaxf(m, al * (v[i] + excl));
    for (int o = 32; o; o >>= 1) m = fmaxf(m, __shfl_xor(m, o));
    float sum = 0.f, num = 0.f;
    for (int i = 0; i < chunk; ++i) {
      int s = s0 + i;
      if (s < L) { float e = __expf(al * (v[i] + excl) - m); sum += e; num += e * (float)s; }
    }
    for (int o = 32; o; o >>= 1) { sum += __shfl_xor(sum, o); num += __shfl_xor(num, o); }
    float win = num / sum;
    float* mk = a.mask[lvl] + (size_t)b * L;
    for (int i = 0; i < chunk; ++i) {
      int s = s0 + i;
      if (s < L) mk[s] = 1.f / (1.f + __expf(-((float)s - win) * be));
    }
  } else {
    int x = bx - 512;
    int lvl, o;
    if (x < 22) { lvl = 0; o = x; }
    else if (x < 79) { lvl = 1; o = x - 22; }
    else if (x < 113) { lvl = 2; o = x - 79; }
    else { lvl = 3; o = x - 113; }
    int O = a.O[lvl];
    const float* iw = a.iw[lvl];
    float m = -1e30f;
    for (int c = lane; c < kC; c += 64) m = fmaxf(m, iw[c * O + o]);
    for (int k = 32; k; k >>= 1) m = fmaxf(m, __shfl_xor(m, k));
    float sum = 0.f;
    for (int c = lane; c < kC; c += 64) sum += __expf(iw[c * O + o] - m);
    for (int k = 32; k; k >>= 1) sum += __shfl_xor(sum, k);
    float inv = 1.f / sum;
    for (int c = lane; c < kC; c += 64) a.sm[lvl][c * O + o] = __expf(iw[c * O + o] - m) * inv;
  }
}

// ---------- ALL levels pred via MFMA ----------
struct PredAllArgs {
  const unsigned short* Xt[4];
  const float* PW[4]; const float* PB[4]; const float* MK[4]; const float* SM[4];
  float* OUT[4];
  int L[4], Lp[4], O[4];
};
__global__ void __launch_bounds__(256) pred_all_kernel(PredAllArgs a) {
  const int lvl = blockIdx.y;
  const int L = a.L[lvl], Lp = a.Lp[lvl], O = a.O[lvl];
  const float* PW = a.PW[lvl];
  const int b = blockIdx.z;
  const int cBase = blockIdx.x * 128;
  const int tid = threadIdx.x;
  const int ln = tid & 63, w = tid >> 6;
  __shared__ short As[64 * 40];
  __shared__ short Bs[128 * 40];
  floatx4 acc[8] = {};
  const unsigned short* Xb = a.Xt[lvl] + ((size_t)b * kCp + cBase) * Lp;
  const float* mk = a.MK[lvl] + (size_t)b * L;
  for (int lc = 0; lc < Lp; lc += 32) {
    {
      int o = tid >> 2, j0 = (tid & 3) * 8;
      alignas(16) unsigned short tmp[8];
#pragma unroll
      for (int j = 0; j < 8; ++j) {
        int l = lc + j0 + j;
        float v = (o < O && l < L) ? PW[(size_t)o * L + l] * mk[l] : 0.f;
        tmp[j] = f2b(v);
      }
      *(uint4*)&As[o * 40 + j0] = *(const uint4*)tmp;
    }
#pragma unroll
    for (int q = 0; q < 2; ++q) {
      int ch = tid * 2 + q;
      int row = ch >> 2, pos = ch & 3;
      *(uint4*)(&Bs[row * 40 + pos * 8]) = *(const uint4*)(Xb + (size_t)row * Lp + lc + pos * 8);
    }
    __syncthreads();
    short8 av = *(const short8*)&As[(w * 16 + (ln & 15)) * 40 + (ln >> 4) * 8];
#pragma unroll
    for (int ni = 0; ni < 8; ++ni) {
      short8 bb = *(const short8*)&Bs[(ni * 16 + (ln & 15)) * 40 + (ln >> 4) * 8];
      acc[ni] = __builtin_amdgcn_mfma_f32_16x16x32_bf16(av, bb, acc[ni], 0, 0, 0);
    }
    __syncthreads();
  }
  const float negln = -logf(10000.f) / (float)O;
#pragma unroll
  for (int ni = 0; ni < 8; ++ni) {
    int c = cBase + ni * 16 + (ln & 15);
    if (c >= kC) continue;
#pragma unroll
    for (int r = 0; r < 4; ++r) {
      int o = w * 16 + (ln >> 4) * 4 + r;
      if (o >= O) continue;
      float dv = __expf(negln * (float)(2 * (o >> 1)));
      float ang = (float)c * dv;
      float pe = (o & 1) ? cosf(ang) : sinf(ang);
      a.OUT[lvl][((size_t)b * O + o) * kC + c] = a.SM[lvl][c * O + o] * (acc[ni][r] + a.PB[lvl][o] + pe);
    }
  }
}

// ---------- fused 3-stage synthesis + transpose: out[b][c][104] ----------
__global__ void __launch_bounds__(256) sfb_fused_kernel(
    const float* __restrict__ P0, const float* __restrict__ P1,
    const float* __restrict__ P2, const float* __restrict__ P3,
    float* __restrict__ out) {
  __shared__ float p0s[22][32], p3s[22][32], p2s[34][32], p1s[57][32];
  __shared__ float r1s[34][32], r2s[58][32];
  __shared__ float outs[104][33];
  int b = blockIdx.y, c0 = blockIdx.x * 32;
  int tid = threadIdx.x;
  int cl = tid & 31, r = tid >> 5;
  int c = c0 + cl;
  bool cv = c < kC;
  for (int o = r; o < 22; o += 8) {
    p0s[o][cl] = cv ? P0[((size_t)b * 22 + o) * kC + c] : 0.f;
    p3s[o][cl] = cv ? P3[((size_t)b * 22 + o) * kC + c] : 0.f;
  }
  for (int o = r; o < 34; o += 8) p2s[o][cl] = cv ? P2[((size_t)b * 34 + o) * kC + c] : 0.f;
  for (int o = r; o < 57; o += 8) p1s[o][cl] = cv ? P1[((size_t)b * 57 + o) * kC + c] : 0.f;
  __syncthreads();
  for (int n = r; n < 34; n += 8) {
    float acc = 0.f;
#pragma unroll
    for (int j = 0; j < 12; ++j) {
      int m = n + j - 1;
      if (m < 0 || (m & 1)) continue;
      int i = m >> 1;
      if (i >= 22) continue;
      acc += c_h0r[j] * p0s[i][cl] + c_h1r[j] * p3s[i][cl];
    }
    r1s[n][cl] = acc;
  }
  __syncthreads();
  for (int n = r; n < 58; n += 8) {
    float acc = 0.f;
#pragma unroll
    for (int j = 0; j < 12; ++j) {
      int m = n + j - 1;
      if (m < 0 || (m & 1)) continue;
      int i = m >> 1;
      if (i >= 34) continue;
      acc += c_h0r[j] * r1s[i][cl] + c_h1r[j] * p2s[i][cl];
    }
    r2s[n][cl] = acc;
  }
  __syncthreads();
  for (int n = r; n < 104; n += 8) {
    float acc = 0.f;
#pragma unroll
    for (int j = 0; j < 12; ++j) {
      int m = n + j - 1;
      if (m < 0 || (m & 1)) continue;
      int i = m >> 1;
      if (i >= 57) continue;
      acc += c_h0r[j] * r2s[i][cl] + c_h1r[j] * p1s[i][cl];
    }
    outs[n][cl] = acc;
  }
  __syncthreads();
  for (int idx = tid; idx < 32 * 104; idx += 256) {
    int ci = idx / 104, n = idx - ci * 104;
    int cg = c0 + ci;
    if (cg < kC) out[((size_t)b * kC + cg) * 104 + n] = outs[n][ci];
  }
}

extern "C" void kernel_launch(void* const* d_in, const int* in_sizes, int n_in,
                              void* d_out, int out_size, void* d_ws, size_t ws_size,
                              hipStream_t stream) {
  (void)in_sizes; (void)n_in; (void)out_size; (void)ws_size;
  const float* x = (const float*)d_in[0];
  auto inp = [&](int lvl, int j) { return (const float*)d_in[1 + 9 * lvl + j]; };

  float* outf = (float*)d_out;
  float* mout = outf + (size_t)kB * kC * 104;
  float* sout = mout + (size_t)kB * kC;

  float* Wp = (float*)d_ws;
  size_t off = 0;
  auto alloc = [&](size_t n) { float* p = Wp + off; off += (n + 63) & ~(size_t)63; return p; };

  // LO1+LO2 first & contiguous: later aliased as concatenated Q bf16 buffer (91 MB >= 88.1 MB)
  float* LO1 = alloc((size_t)kB * 365 * kC);
  float* LO2 = alloc((size_t)kB * 188 * kC);
  unsigned short* Xt1 = (unsigned short*)alloc((size_t)kB * kCp * 384 / 2);
  unsigned short* Xt2 = (unsigned short*)alloc((size_t)kB * kCp * 256 / 2);
  unsigned short* Xt0 = (unsigned short*)alloc((size_t)kB * kCp * 128 / 2);
  unsigned short* Xt3 = (unsigned short*)alloc((size_t)kB * kCp * 128 / 2);
  unsigned short* KbfAll = (unsigned short*)alloc((size_t)kB * kCp * 896 / 2);
  unsigned short* Wpv[8];
  for (int i = 0; i < 8; ++i)
    Wpv[i] = (unsigned short*)alloc((size_t)384 * 384 / 2);
  float* wgtAll = alloc((size_t)kB * (99 + 365 + 188 + 99));
  float* M0 = alloc((size_t)kB * 99);  float* M1 = alloc((size_t)kB * 365);
  float* M2 = alloc((size_t)kB * 188); float* M3 = alloc((size_t)kB * 99);
  float* S0 = alloc((size_t)kC * 22);  float* S1 = alloc((size_t)kC * 57);
  float* S2 = alloc((size_t)kC * 34);  float* S3 = alloc((size_t)kC * 22);
  float* P0 = alloc((size_t)kB * 22 * kC); float* P1 = alloc((size_t)kB * 57 * kC);
  float* P2 = alloc((size_t)kB * 34 * kC); float* P3 = alloc((size_t)kB * 22 * kC);
  float* ps   = alloc((size_t)kB * 8 * kC);
  float* ps2  = alloc((size_t)kB * 8 * kC);
  float* meanw = alloc((size_t)kB * kC);
  float* invw  = alloc((size_t)kB * kC);
  unsigned short* QbfAll = (unsigned short*)LO1;   // alias over LO1+LO2 (dead before qk_all)

  const int Lc[4]  = {99, 365, 188, 99};
  const int Lpv[4] = {128, 384, 256, 128};
  const int Ov[4]  = {22, 57, 34, 22};
  const int prefLp[4] = {0, 128, 512, 768};
  const int wOff[4] = {0, 99, 99 + 365, 99 + 365 + 188};
  unsigned short* Qlvl[4]; unsigned short* Klvl[4];
  for (int i = 0; i < 4; ++i) {
    Qlvl[i] = QbfAll + (size_t)kB * kCp * prefLp[i];
    Klvl[i] = KbfAll + (size_t)kB * kCp * prefLp[i];
  }
  const unsigned short* Xts[4] = {Xt0, Xt1, Xt2, Xt3};
  float* masks[4] = {M0, M1, M2, M3};
  float* smws[4]  = {S0, S1, S2, S3};
  float* preds[4] = {P0, P1, P2, P3};

  // 1) mean/std
  partial_ms_kernel<<<dim3(kB, 8, 3), 128, 0, stream>>>(x, ps, ps2);
  finalize_ms_kernel<<<(kB * kC + 255) / 256, 256, 0, stream>>>(ps, ps2, mout, sout, meanw, invw);

  // 2) fused DWT cascade
  dwt_fused_kernel<true, true, false><<<dim3(6, kCp / 64, kB), 256, 0, stream>>>(
      x, meanw, invw, LO1, nullptr, Xt1, kN0, 365, 384);
  dwt_fused_kernel<false, true, false><<<dim3(4, kCp / 64, kB), 256, 0, stream>>>(
      LO1, nullptr, nullptr, LO2, nullptr, Xt2, 365, 188, 256);
  dwt_fused_kernel<false, false, true><<<dim3(2, kCp / 64, kB), 256, 0, stream>>>(
      LO2, nullptr, nullptr, nullptr, Xt0, Xt3, 188, 99, 128);

  // 3) weight conversions (one launch) + wgt zero
  {
    WcArgs wa;
    for (int i = 0; i < 4; ++i) {
      wa.src[2 * i] = inp(i, 0); wa.src[2 * i + 1] = inp(i, 2);
      wa.dst[2 * i] = Wpv[2 * i]; wa.dst[2 * i + 1] = Wpv[2 * i + 1];
      wa.L[2 * i] = wa.L[2 * i + 1] = Lc[i];
      wa.Lp[2 * i] = wa.Lp[2 * i + 1] = Lpv[i];
    }
    wconv_all_kernel<<<dim3(576, 8), 256, 0, stream>>>(wa);
  }
  hipMemsetAsync(wgtAll, 0, (size_t)kB * (99 + 365 + 188 + 99) * sizeof(float), stream);

  // 4) all-level fused Q+K projections (one launch; runs after dwt3 so LO1/LO2 alias is safe)
  {
    QKAllArgs qa;
    for (int i = 0; i < 4; ++i) {
      qa.W[2 * i] = Wpv[2 * i]; qa.W[2 * i + 1] = Wpv[2 * i + 1];
      qa.bias[2 * i] = inp(i, 1); qa.bias[2 * i + 1] = inp(i, 3);
      qa.Y[2 * i] = Qlvl[i]; qa.Y[2 * i + 1] = Klvl[i];
      qa.Xt[i] = Xts[i]; qa.Lp[i] = Lpv[i]; qa.L[i] = Lc[i];
    }
    qa.yOff[0] = 0; qa.yOff[1] = 1; qa.yOff[2] = 4; qa.yOff[3] = 6;  // p-tiles: 1,3,2,1
    qk_all_kernel<<<dim3(kCp / 128, 7, kB), 512, 0, stream>>>(qa);
  }

  // 5) all-level scores (one launch, 1D grid + XCD swizzle)
  {
    ScAllArgs sa;
    for (int i = 0; i < 4; ++i) {
      sa.Q[i] = Qlvl[i]; sa.K[i] = Klvl[i];
      sa.wgt[i] = wgtAll + (size_t)kB * wOff[i];
      sa.Lp[i] = Lpv[i]; sa.L[i] = Lc[i];
      sa.scale[i] = 1.0f / sqrtf((float)Lc[i]);
    }
    sa.tOff[0] = 0; sa.tOff[1] = 1; sa.tOff[2] = 10; sa.tOff[3] = 14;  // 1,9,4,1 tiles
    scores_all_kernel<<<15 * kB, 256, 0, stream>>>(sa);
  }

  // 6) window masks + channel softmax (merged)
  {
    WinIwArgs wa;
    for (int i = 0; i < 4; ++i) {
      wa.wgt[i] = wgtAll + (size_t)kB * wOff[i];
      wa.al[i] = inp(i, 7); wa.be[i] = inp(i, 8);
      wa.mask[i] = masks[i]; wa.L[i] = Lc[i];
      wa.iw[i] = inp(i, 6); wa.sm[i] = smws[i]; wa.O[i] = Ov[i];
    }
    winiw_kernel<<<512 + 135, 64, 0, stream>>>(wa);
  }

  // 7) all-level pred projections (one launch)
  {
    PredAllArgs pa;
    for (int i = 0; i < 4; ++i) {
      pa.Xt[i] = Xts[i]; pa.PW[i] = inp(i, 4); pa.PB[i] = inp(i, 5);
      pa.MK[i] = masks[i]; pa.SM[i] = smws[i]; pa.OUT[i] = preds[i];
      pa.L[i] = Lc[i]; pa.Lp[i] = Lpv[i]; pa.O[i] = Ov[i];
    }
    pred_all_kernel<<<dim3(kCp / 128, 4, kB), 256, 0, stream>>>(pa);
  }

  // 8) fused reconstruction + transpose
  sfb_fused_kernel<<<dim3(11, kB), 256, 0, stream>>>(P0, P1, P2, P3, outf);
}

// Round 6
// 775.977 us; speedup vs baseline: 1.0068x; 1.0068x over previous
//
#include <hip/hip_runtime.h>
#include <hip/hip_bf16.h>
#include <math.h>

namespace {
constexpr int kB  = 128;
constexpr int kC  = 321;
constexpr int kN0 = 720;
constexpr int kCp = 384;   // padded channel dim for MFMA
}

typedef __attribute__((ext_vector_type(8))) short short8;
typedef __attribute__((ext_vector_type(4))) float floatx4;
typedef __attribute__((ext_vector_type(16))) float floatx16;

__device__ __forceinline__ floatx16 mfma32(short8 a, short8 b, floatx16 c) {
  return __builtin_amdgcn_mfma_f32_32x32x16_bf16(a, b, c, 0, 0, 0);
}

// db6 analysis filters (H0 = lowpass, H1 = qmf highpass), and reversed copies
__constant__ float c_h0[12] = {
  0.11154074335008017f, 0.4946238903983854f, 0.7511339080215775f,
  0.3152503517092432f, -0.22626469396516913f, -0.12976686756709563f,
  0.09750160558707936f, 0.02752286553001629f, -0.031582039318031156f,
  0.0005538422009938016f, 0.004777257511010651f, -0.00107730108499558f};
__constant__ float c_h1[12] = {
  -0.00107730108499558f, -0.004777257511010651f, 0.0005538422009938016f,
  0.031582039318031156f, 0.02752286553001629f, -0.09750160558707936f,
  -0.12976686756709563f, 0.22626469396516913f, 0.3152503517092432f,
  -0.7511339080215775f, 0.4946238903983854f, -0.11154074335008017f};
__constant__ float c_h0r[12] = {
  -0.00107730108499558f, 0.004777257511010651f, 0.0005538422009938016f,
  -0.031582039318031156f, 0.02752286553001629f, 0.09750160558707936f,
  -0.12976686756709563f, -0.22626469396516913f, 0.3152503517092432f,
  0.7511339080215775f, 0.4946238903983854f, 0.11154074335008017f};
__constant__ float c_h1r[12] = {
  -0.11154074335008017f, 0.4946238903983854f, -0.7511339080215775f,
  0.3152503517092432f, 0.22626469396516913f, -0.12976686756709563f,
  -0.09750160558707936f, 0.02752286553001629f, 0.031582039318031156f,
  0.0005538422009938016f, -0.004777257511010651f, -0.00107730108499558f};

__device__ __forceinline__ float fast_tanh(float x) {
  float e = __expf(2.f * x);
  return 1.f - 2.f / (e + 1.f);
}
__device__ __forceinline__ unsigned short f2b(float f) {
  __hip_bfloat16 h = __float2bfloat16(f);
  return __builtin_bit_cast(unsigned short, h);
}

// async global->LDS, 16B per lane; LDS dest = wave-uniform base + lane*16
__device__ __forceinline__ void gload16(const unsigned short* g, short* l) {
  __builtin_amdgcn_global_load_lds(
      (const __attribute__((address_space(1))) unsigned int*)g,
      (__attribute__((address_space(3))) unsigned int*)l, 16, 0, 0);
}

// ---------- mean/std over time axis: 8 chunks x 90 t, unrolled for MLP ----------
__global__ void __launch_bounds__(128) partial_ms_kernel(
    const float* __restrict__ x, float* __restrict__ ps, float* __restrict__ ps2) {
  int b = blockIdx.x, chunk = blockIdx.y;
  int c = blockIdx.z * 128 + threadIdx.x;
  if (c >= kC) return;
  const float* xb = x + (size_t)b * kN0 * kC + c;
  int t0 = chunk * 90;
  float s = 0.f, s2 = 0.f;
#pragma unroll 15
  for (int i = 0; i < 90; ++i) {
    float v = xb[(size_t)(t0 + i) * kC];
    s += v; s2 += v * v;
  }
  ps [(b * 8 + chunk) * kC + c] = s;
  ps2[(b * 8 + chunk) * kC + c] = s2;
}

__global__ void __launch_bounds__(256) finalize_ms_kernel(
    const float* __restrict__ ps, const float* __restrict__ ps2,
    float* __restrict__ mout, float* __restrict__ sout,
    float* __restrict__ meanw, float* __restrict__ invw) {
  int i = blockIdx.x * 256 + threadIdx.x;
  if (i >= kB * kC) return;
  int b = i / kC, c = i - b * kC;
  float s = 0.f, s2 = 0.f;
#pragma unroll
  for (int k = 0; k < 8; ++k) { s += ps[(b * 8 + k) * kC + c]; s2 += ps2[(b * 8 + k) * kC + c]; }
  float mean = s * (1.f / (float)kN0);
  float var = s2 * (1.f / (float)kN0) - mean * mean;
  float sd = sqrtf(var + 1e-5f);
  mout[i] = mean; sout[i] = sd;
  meanw[i] = mean; invw[i] = 1.f / sd;
}

__device__ __forceinline__ int sym_reflect(int t, int N) {
  t = (t < 0) ? (-1 - t) : t;
  t = (t >= N) ? (2 * N - 1 - t) : t;
  return t;
}

// ---------- fused tiled DWT level ----------
template <bool NORM, bool LO_F32, bool LO_BF16>
__global__ void __launch_bounds__(256) dwt_fused_kernel(
    const float* __restrict__ in, const float* __restrict__ meanw,
    const float* __restrict__ invw, float* __restrict__ loF,
    unsigned short* __restrict__ loB, unsigned short* __restrict__ hiB,
    int N, int L, int Lp) {
  __shared__ float xs[138][64];
  __shared__ unsigned short los[64][72];
  __shared__ unsigned short his[64][72];
  const int b = blockIdx.z;
  const int n0 = blockIdx.x * 64, c0 = blockIdx.y * 64;
  const int tid = threadIdx.x;
  const int cl = tid & 63, wv = tid >> 6;
  const int c = c0 + cl;
  const int t0 = 2 * n0 - 10;
  const float* ib = in + (size_t)b * N * kC;
  float mean = 0.f, inv = 1.f;
  if (NORM && c < kC) { mean = meanw[b * kC + c]; inv = invw[b * kC + c]; }
  for (int r = wv; r < 138; r += 4) {
    int t = sym_reflect(t0 + r, N);
    float v = (c < kC) ? ib[(size_t)t * kC + c] : 0.f;
    if (NORM) v = (v - mean) * inv;
    xs[r][cl] = v;
  }
  __syncthreads();
#pragma unroll 4
  for (int k = 0; k < 16; ++k) {
    int nl = wv + 4 * k;
    int n = n0 + nl;
    float a0 = 0.f, a1 = 0.f;
    int base = 2 * nl;
#pragma unroll
    for (int j = 0; j < 12; ++j) {
      float v = xs[base + j][cl];
      a0 += v * c_h0[j]; a1 += v * c_h1[j];
    }
    bool valid = (n < L) && (c < kC);
    if (LO_F32 && valid) loF[((size_t)b * L + n) * kC + c] = a0;
    if (LO_BF16) los[cl][nl] = f2b(valid ? a0 : 0.f);
    his[cl][nl] = f2b(valid ? a1 : 0.f);
  }
  __syncthreads();
  int row = tid >> 2, part = tid & 3;
  size_t dst = ((size_t)b * kCp + c0 + row) * Lp + n0 + part * 16;
  *(uint4*)(hiB + dst)     = *(const uint4*)&his[row][part * 16];
  *(uint4*)(hiB + dst + 8) = *(const uint4*)&his[row][part * 16 + 8];
  if (LO_BF16) {
    *(uint4*)(loB + dst)     = *(const uint4*)&los[row][part * 16];
    *(uint4*)(loB + dst + 8) = *(const uint4*)&los[row][part * 16 + 8];
  }
}

// ---------- all-level weight fp32 [L][L] -> bf16 [Lp][Lp] zero-padded ----------
struct WcArgs { const float* src[8]; unsigned short* dst[8]; int L[8]; int Lp[8]; };
__global__ void __launch_bounds__(256) wconv_all_kernel(WcArgs a) {
  int lvl = blockIdx.y;
  int Lp = a.Lp[lvl], L = a.L[lvl];
  int i = blockIdx.x * 256 + threadIdx.x;
  if (i >= Lp * Lp) return;
  int p = i / Lp, l = i - p * Lp;
  a.dst[lvl][i] = f2b((p < L && l < L) ? a.src[lvl][(size_t)p * L + l] : 0.f);
}

// ---------- ALL levels Q+K projections fused; 32x32x16 MFMA; K-step 32;
// triple-buffered 2-deep counted-vmcnt pipeline. Block 512 thr = 8 waves
// (4p x 2c), tile 128p x 128c, both Q and K outputs (X staged once).
// 16B-chunk XOR swizzle with key (row>>1)&3 (decorrelated from row parity ->
// 8 dwords/bank, balanced): inverse-permuted gload source, linear LDS dest,
// per-lane-constant read chunk. Epilogue: padded LDS bounce -> uint4 stores. ----------
struct QKAllArgs {
  const unsigned short* W[8];     // [2*lvl+sel]
  const unsigned short* Xt[4];
  const float* bias[8];
  unsigned short* Y[8];
  int Lp[4], L[4], yOff[4];       // yOff = {0,1,4,6} (p-tiles per level: 1,3,2,1)
};
__global__ void __launch_bounds__(512, 4) qk_all_kernel(QKAllArgs a) {
  const int y = blockIdx.y;
  const int lvl = (y >= a.yOff[1]) + (y >= a.yOff[2]) + (y >= a.yOff[3]);
  const int Lp = a.Lp[lvl], L = a.L[lvl];
  const int pBase = (y - a.yOff[lvl]) * 128;
  const unsigned short* W0 = a.W[2 * lvl]     + (size_t)pBase * Lp;
  const unsigned short* W1 = a.W[2 * lvl + 1] + (size_t)pBase * Lp;
  const int b = blockIdx.z;
  const int cBase = blockIdx.x * 128;
  const int tid = threadIdx.x;
  const int ln = tid & 63, w = tid >> 6;
  const int wm = w & 3, wn = w >> 2;        // 4 p-waves x 2 c-waves
  __shared__ __align__(16) short smem[3 * 384 * 32];   // 72 KB: 3 phases x (Aq128|Ak128|X128) x 32
  floatx16 accQ[2] = {}, accK[2] = {};      // [c-frag], 64 VGPR
  const unsigned short* Xb = a.Xt[lvl] + ((size_t)b * kCp + cBase) * Lp;
  // staging: 24 gload16/phase, 3 per wave; lane -> row o*16+(ln>>2), phys
  // chunk ln&3; source logical chunk = phys ^ ((row>>1)&3) = (ln&3)^((ln>>3)&3)
  const int lr = ln >> 2;
  const int srcC = ((ln & 3) ^ ((ln >> 3) & 3)) * 8;
  const unsigned short* srcs[3];
#pragma unroll
  for (int i = 0; i < 3; ++i) {
    int o = w * 3 + i;          // 0..23
    int rr = o * 16 + lr;
    const unsigned short* s = (o < 8)  ? (W0 + (size_t)rr * Lp)
                            : (o < 16) ? (W1 + (size_t)(rr - 128) * Lp)
                                       : (Xb + (size_t)(rr - 256) * Lp);
    srcs[i] = s + srcC;
  }
  auto stage = [&](int buf, int lc) {
#pragma unroll
    for (int i = 0; i < 3; ++i)
      gload16(srcs[i] + lc, &smem[buf * 12288 + (w * 3 + i) * 512]);
  };
  // fragment read geometry (A: row=ln&31, k-group=(ln>>5)*8; same for B);
  // read key (row>>1)&3 = (ln>>1)&3 for all fragment rows (row-base mult of 32)
  const int rl = ln & 31, sel = ln >> 5;
  const int sw = (ln >> 1) & 3;
  const int kc0 = (sel ^ sw) * 8;           // k-sub 0 phys chunk
  const int kc1 = ((2 + sel) ^ sw) * 8;     // k-sub 1 phys chunk
  const int aOff  = (wm * 32 + rl) * 32;
  const int akOff = 4096 + aOff;
  const int bOff0 = 8192 + (wn * 64 + rl) * 32;
  const int bOff1 = bOff0 + 1024;           // +32 rows
  const int nt = Lp >> 5;
  stage(0, 0);
  stage(1, 32);
  int bufn = 2, lc = 64, bc = 0;
  for (int kt = 0; kt < nt; ++kt) {
    if (kt + 1 < nt) asm volatile("s_waitcnt vmcnt(3)" ::: "memory");
    else             asm volatile("s_waitcnt vmcnt(0)" ::: "memory");
    __builtin_amdgcn_s_barrier();
    __builtin_amdgcn_sched_barrier(0);
    if (kt + 2 < nt) {
      stage(bufn, lc);
      lc += 32;
      bufn = (bufn == 2) ? 0 : bufn + 1;
    }
    const int ph = bc * 12288;
    short8 a0 = *(const short8*)&smem[ph + aOff + kc0];
    short8 k0 = *(const short8*)&smem[ph + akOff + kc0];
    short8 b0 = *(const short8*)&smem[ph + bOff0 + kc0];
    short8 b1 = *(const short8*)&smem[ph + bOff1 + kc0];
    accQ[0] = mfma32(a0, b0, accQ[0]); accQ[1] = mfma32(a0, b1, accQ[1]);
    accK[0] = mfma32(k0, b0, accK[0]); accK[1] = mfma32(k0, b1, accK[1]);
    a0 = *(const short8*)&smem[ph + aOff + kc1];
    k0 = *(const short8*)&smem[ph + akOff + kc1];
    b0 = *(const short8*)&smem[ph + bOff0 + kc1];
    b1 = *(const short8*)&smem[ph + bOff1 + kc1];
    accQ[0] = mfma32(a0, b0, accQ[0]); accQ[1] = mfma32(a0, b1, accQ[1]);
    accK[0] = mfma32(k0, b0, accK[0]); accK[1] = mfma32(k0, b1, accK[1]);
    bc = (bc == 2) ? 0 : bc + 1;
  }
  __syncthreads();
  // epilogue: bounce [128p][136c-pad] (uint4-aligned rows), then coalesced stores.
  // Q zeroes pad rows p>=L; K zeroes pad cols c>=kC.
  short* bnc = smem;
  const int cl = wn * 64 + rl;
  const bool c0v = (cBase + cl) < kC, c1v = (cBase + cl + 32) < kC;
  {
    const float* bias = a.bias[2 * lvl];
#pragma unroll
    for (int reg = 0; reg < 16; ++reg) {
      int pl = wm * 32 + (reg & 3) + 8 * (reg >> 2) + 4 * sel;
      int p = pBase + pl;
      bool pv = p < L;
      float bq = pv ? bias[p] : 0.f;
      float v0 = fast_tanh(accQ[0][reg] + bq); if (!pv) v0 = 0.f;
      float v1 = fast_tanh(accQ[1][reg] + bq); if (!pv) v1 = 0.f;
      bnc[pl * 136 + cl]      = (short)f2b(v0);
      bnc[pl * 136 + cl + 32] = (short)f2b(v1);
    }
  }
  __syncthreads();
  {
    unsigned short* Yd = a.Y[2 * lvl];
#pragma unroll
    for (int j = 0; j < 4; ++j) {
      int idx = tid + j * 512;
      int row = idx >> 4, ch = idx & 15;
      *(uint4*)(Yd + ((size_t)b * Lp + pBase + row) * kCp + cBase + ch * 8) =
          *(const uint4*)&bnc[row * 136 + ch * 8];
    }
  }
  __syncthreads();
  {
    const float* bias = a.bias[2 * lvl + 1];
#pragma unroll
    for (int reg = 0; reg < 16; ++reg) {
      int pl = wm * 32 + (reg & 3) + 8 * (reg >> 2) + 4 * sel;
      int p = pBase + pl;
      bool pv = p < L;
      float bq = pv ? bias[p] : 0.f;
      float v0 = fast_tanh(accK[0][reg] + bq); if (!c0v) v0 = 0.f;
      float v1 = fast_tanh(accK[1][reg] + bq); if (!c1v) v1 = 0.f;
      bnc[pl * 136 + cl]      = (short)f2b(v0);
      bnc[pl * 136 + cl + 32] = (short)f2b(v1);
    }
  }
  __syncthreads();
  {
    unsigned short* Yd = a.Y[2 * lvl + 1];
#pragma unroll
    for (int j = 0; j < 4; ++j) {
      int idx = tid + j * 512;
      int row = idx >> 4, ch = idx & 15;
      *(uint4*)(Yd + ((size_t)b * Lp + pBase + row) * kCp + cBase + ch * 8) =
          *(const uint4*)&bnc[row * 136 + ch * 8];
    }
  }
}

// ---------- ALL levels scores; 32x32x16 MFMA; same tri-buffer pipeline.
// Block 256 thr = 4 waves (2l x 2s), tile 128l x 128s. XCD-swizzled 1D grid. ----------
struct ScAllArgs {
  const unsigned short* Q[4]; const unsigned short* K[4];
  float* wgt[4];
  int Lp[4], L[4], tOff[4];     // tOff = {0,1,10,14}
  float scale[4];
};
__global__ void __launch_bounds__(256, 4) scores_all_kernel(ScAllArgs a) {
  const int bid = blockIdx.x;                 // 0..1919
  const int wg = (bid & 7) * 240 + (bid >> 3);
  const int t = wg % 15;
  const int b = wg / 15;
  const int lvl = (t >= a.tOff[1]) + (t >= a.tOff[2]) + (t >= a.tOff[3]);
  const int rel = t - a.tOff[lvl];
  const int Lp = a.Lp[lvl], L = a.L[lvl];
  const int pt = Lp >> 7;
  const int sBase = (rel % pt) * 128;
  const int lBase = (rel / pt) * 128;
  const int tid = threadIdx.x;
  const int ln = tid & 63, w = tid >> 6;
  const int wm = w & 1, wn = w >> 1;          // 2 l-waves x 2 s-waves
  __shared__ __align__(16) short smem[3 * 256 * 32];   // 48 KB: 3 phases x (Q128|K128) x 32
  __shared__ float red[128];
  floatx16 acc[2][2] = {};                    // [l-frag][s-frag]
  const unsigned short* Qp = a.Q[lvl] + ((size_t)b * Lp + lBase) * kCp;
  const unsigned short* Kp = a.K[lvl] + ((size_t)b * Lp + sBase) * kCp;
  const int lr = ln >> 2;
  const int srcC = ((ln & 3) ^ ((ln >> 3) & 3)) * 8;
  const unsigned short* srcs[4];
#pragma unroll
  for (int i = 0; i < 4; ++i) {
    int o = w * 4 + i;          // 0..15
    int rr = o * 16 + lr;
    srcs[i] = ((o < 8) ? (Qp + (size_t)rr * kCp)
                       : (Kp + (size_t)(rr - 128) * kCp)) + srcC;
  }
  auto stage = [&](int buf, int cc) {
#pragma unroll
    for (int i = 0; i < 4; ++i)
      gload16(srcs[i] + cc, &smem[buf * 8192 + (w * 4 + i) * 512]);
  };
  const int rl = ln & 31, sel = ln >> 5;
  const int sw = (ln >> 1) & 3;
  const int kc0 = (sel ^ sw) * 8;
  const int kc1 = ((2 + sel) ^ sw) * 8;
  const int aOff0 = (wm * 64 + rl) * 32, aOff1 = aOff0 + 1024;
  const int bOff0 = 4096 + (wn * 64 + rl) * 32, bOff1 = bOff0 + 1024;
  if (tid < 128) red[tid] = 0.f;
  const int nt = kCp >> 5;   // 12
  stage(0, 0);
  stage(1, 32);
  int bufn = 2, cc = 64, bc = 0;
  for (int kt = 0; kt < nt; ++kt) {
    if (kt + 1 < nt) asm volatile("s_waitcnt vmcnt(4)" ::: "memory");
    else             asm volatile("s_waitcnt vmcnt(0)" ::: "memory");
    __builtin_amdgcn_s_barrier();
    __builtin_amdgcn_sched_barrier(0);
    if (kt + 2 < nt) {
      stage(bufn, cc);
      cc += 32;
      bufn = (bufn == 2) ? 0 : bufn + 1;
    }
    const int ph = bc * 8192;
    short8 a0 = *(const short8*)&smem[ph + aOff0 + kc0];
    short8 a1 = *(const short8*)&smem[ph + aOff1 + kc0];
    short8 b0 = *(const short8*)&smem[ph + bOff0 + kc0];
    short8 b1 = *(const short8*)&smem[ph + bOff1 + kc0];
    acc[0][0] = mfma32(a0, b0, acc[0][0]); acc[0][1] = mfma32(a0, b1, acc[0][1]);
    acc[1][0] = mfma32(a1, b0, acc[1][0]); acc[1][1] = mfma32(a1, b1, acc[1][1]);
    a0 = *(const short8*)&smem[ph + aOff0 + kc1];
    a1 = *(const short8*)&smem[ph + aOff1 + kc1];
    b0 = *(const short8*)&smem[ph + bOff0 + kc1];
    b1 = *(const short8*)&smem[ph + bOff1 + kc1];
    acc[0][0] = mfma32(a0, b0, acc[0][0]); acc[0][1] = mfma32(a0, b1, acc[0][1]);
    acc[1][0] = mfma32(a1, b0, acc[1][0]); acc[1][1] = mfma32(a1, b1, acc[1][1]);
    bc = (bc == 2) ? 0 : bc + 1;
  }
  const float scale = a.scale[lvl];
#pragma unroll
  for (int sf = 0; sf < 2; ++sf) {
    float p = 0.f;
#pragma unroll
    for (int lf = 0; lf < 2; ++lf)
#pragma unroll
      for (int reg = 0; reg < 16; ++reg)
        p += fast_tanh(acc[lf][sf][reg] * scale);
    p += __shfl_xor(p, 32);
    if (ln < 32) atomicAdd(&red[wn * 64 + sf * 32 + ln], p);
  }
  __syncthreads();
  if (tid < 128) {
    int s = sBase + tid;
    if (s < L) atomicAdd(&a.wgt[lvl][(size_t)b * L + s], red[tid]);
  }
}

// ---------- merged window mask + iw softmax (one launch) ----------
struct WinIwArgs {
  const float* wgt[4]; const float* al[4]; const float* be[4];
  float* mask[4]; int L[4];
  const float* iw[4]; float* sm[4]; int O[4];
};
__global__ void __launch_bounds__(64) winiw_kernel(WinIwArgs a) {
  int bx = blockIdx.x;
  int lane = threadIdx.x;
  if (bx < 512) {
    int lvl = bx >> 7, b = bx & 127;
    int L = a.L[lvl];
    const float* wgt = a.wgt[lvl] + (size_t)b * L;
    float al = a.al[lvl][0], be = a.be[lvl][0];
    float invL = 1.f / (float)L;
    int chunk = (L + 63) >> 6;            // <= 6
    int s0 = lane * chunk;
    float v[6];
    float csum = 0.f;
    for (int i = chunk - 1; i >= 0; --i) {
      int s = s0 + i;
      float xv = (s < L) ? wgt[s] * invL : 0.f;
      csum += xv; v[i] = csum;
    }
    float tot = csum;
    for (int o = 1; o < 64; o <<= 1) {
      float t = __shfl_down(tot, o);
      if (lane + o < 64) tot += t;
    }
    float excl = tot - csum;
    float m = -1e30f;
    for (int i = 0; i < chunk; ++i)
      if (s0 + i < L) m = fmaxf(m, al * (v[i] + excl));
    for (int o = 32; o; o >>= 1) m = fmaxf(m, __shfl_xor(m, o));
    float sum = 0.f, num = 0.f;
    for (int i = 0; i < chunk; ++i) {
      int s = s0 + i;
      if (s < L) { float e = __expf(al * (v[i] + excl) - m); sum += e; num += e * (float)s; }
    }
    for (int o = 32; o; o >>= 1) { sum += __shfl_xor(sum, o); num += __shfl_xor(num, o); }
    float win = num / sum;
    float* mk = a.mask[lvl] + (size_t)b * L;
    for (int i = 0; i < chunk; ++i) {
      int s = s0 + i;
      if (s < L) mk[s] = 1.f / (1.f + __expf(-((float)s - win) * be));
    }
  } else {
    int x = bx - 512;
    int lvl, o;
    if (x < 22) { lvl = 0; o = x; }
    else if (x < 79) { lvl = 1; o = x - 22; }
    else if (x < 113) { lvl = 2; o = x - 79; }
    else { lvl = 3; o = x - 113; }
    int O = a.O[lvl];
    const float* iw = a.iw[lvl];
    float m = -1e30f;
    for (int c = lane; c < kC; c += 64) m = fmaxf(m, iw[c * O + o]);
    for (int k = 32; k; k >>= 1) m = fmaxf(m, __shfl_xor(m, k));
    float sum = 0.f;
    for (int c = lane; c < kC; c += 64) sum += __expf(iw[c * O + o] - m);
    for (int k = 32; k; k >>= 1) sum += __shfl_xor(sum, k);
    float inv = 1.f / sum;
    for (int c = lane; c < kC; c += 64) a.sm[lvl][c * O + o] = __expf(iw[c * O + o] - m) * inv;
  }
}

// ---------- ALL levels pred via MFMA ----------
struct PredAllArgs {
  const unsigned short* Xt[4];
  const float* PW[4]; const float* PB[4]; const float* MK[4]; const float* SM[4];
  float* OUT[4];
  int L[4], Lp[4], O[4];
};
__global__ void __launch_bounds__(256) pred_all_kernel(PredAllArgs a) {
  const int lvl = blockIdx.y;
  const int L = a.L[lvl], Lp = a.Lp[lvl], O = a.O[lvl];
  const float* PW = a.PW[lvl];
  const int b = blockIdx.z;
  const int cBase = blockIdx.x * 128;
  const int tid = threadIdx.x;
  const int ln = tid & 63, w = tid >> 6;
  __shared__ short As[64 * 40];
  __shared__ short Bs[128 * 40];
  floatx4 acc[8] = {};
  const unsigned short* Xb = a.Xt[lvl] + ((size_t)b * kCp + cBase) * Lp;
  const float* mk = a.MK[lvl] + (size_t)b * L;
  for (int lc = 0; lc < Lp; lc += 32) {
    {
      int o = tid >> 2, j0 = (tid & 3) * 8;
      alignas(16) unsigned short tmp[8];
#pragma unroll
      for (int j = 0; j < 8; ++j) {
        int l = lc + j0 + j;
        float v = (o < O && l < L) ? PW[(size_t)o * L + l] * mk[l] : 0.f;
        tmp[j] = f2b(v);
      }
      *(uint4*)&As[o * 40 + j0] = *(const uint4*)tmp;
    }
#pragma unroll
    for (int q = 0; q < 2; ++q) {
      int ch = tid * 2 + q;
      int row = ch >> 2, pos = ch & 3;
      *(uint4*)(&Bs[row * 40 + pos * 8]) = *(const uint4*)(Xb + (size_t)row * Lp + lc + pos * 8);
    }
    __syncthreads();
    short8 av = *(const short8*)&As[(w * 16 + (ln & 15)) * 40 + (ln >> 4) * 8];
#pragma unroll
    for (int ni = 0; ni < 8; ++ni) {
      short8 bb = *(const short8*)&Bs[(ni * 16 + (ln & 15)) * 40 + (ln >> 4) * 8];
      acc[ni] = __builtin_amdgcn_mfma_f32_16x16x32_bf16(av, bb, acc[ni], 0, 0, 0);
    }
    __syncthreads();
  }
  const float negln = -logf(10000.f) / (float)O;
#pragma unroll
  for (int ni = 0; ni < 8; ++ni) {
    int c = cBase + ni * 16 + (ln & 15);
    if (c >= kC) continue;
#pragma unroll
    for (int r = 0; r < 4; ++r) {
      int o = w * 16 + (ln >> 4) * 4 + r;
      if (o >= O) continue;
      float dv = __expf(negln * (float)(2 * (o >> 1)));
      float ang = (float)c * dv;
      float pe = (o & 1) ? cosf(ang) : sinf(ang);
      a.OUT[lvl][((size_t)b * O + o) * kC + c] = a.SM[lvl][c * O + o] * (acc[ni][r] + a.PB[lvl][o] + pe);
    }
  }
}

// ---------- fused 3-stage synthesis + transpose: out[b][c][104] ----------
__global__ void __launch_bounds__(256) sfb_fused_kernel(
    const float* __restrict__ P0, const float* __restrict__ P1,
    const float* __restrict__ P2, const float* __restrict__ P3,
    float* __restrict__ out) {
  __shared__ float p0s[22][32], p3s[22][32], p2s[34][32], p1s[57][32];
  __shared__ float r1s[34][32], r2s[58][32];
  __shared__ float outs[104][33];
  int b = blockIdx.y, c0 = blockIdx.x * 32;
  int tid = threadIdx.x;
  int cl = tid & 31, r = tid >> 5;
  int c = c0 + cl;
  bool cv = c < kC;
  for (int o = r; o < 22; o += 8) {
    p0s[o][cl] = cv ? P0[((size_t)b * 22 + o) * kC + c] : 0.f;
    p3s[o][cl] = cv ? P3[((size_t)b * 22 + o) * kC + c] : 0.f;
  }
  for (int o = r; o < 34; o += 8) p2s[o][cl] = cv ? P2[((size_t)b * 34 + o) * kC + c] : 0.f;
  for (int o = r; o < 57; o += 8) p1s[o][cl] = cv ? P1[((size_t)b * 57 + o) * kC + c] : 0.f;
  __syncthreads();
  for (int n = r; n < 34; n += 8) {
    float acc = 0.f;
#pragma unroll
    for (int j = 0; j < 12; ++j) {
      int m = n + j - 1;
      if (m < 0 || (m & 1)) continue;
      int i = m >> 1;
      if (i >= 22) continue;
      acc += c_h0r[j] * p0s[i][cl] + c_h1r[j] * p3s[i][cl];
    }
    r1s[n][cl] = acc;
  }
  __syncthreads();
  for (int n = r; n < 58; n += 8) {
    float acc = 0.f;
#pragma unroll
    for (int j = 0; j < 12; ++j) {
      int m = n + j - 1;
      if (m < 0 || (m & 1)) continue;
      int i = m >> 1;
      if (i >= 34) continue;
      acc += c_h0r[j] * r1s[i][cl] + c_h1r[j] * p2s[i][cl];
    }
    r2s[n][cl] = acc;
  }
  __syncthreads();
  for (int n = r; n < 104; n += 8) {
    float acc = 0.f;
#pragma unroll
    for (int j = 0; j < 12; ++j) {
      int m = n + j - 1;
      if (m < 0 || (m & 1)) continue;
      int i = m >> 1;
      if (i >= 57) continue;
      acc += c_h0r[j] * r2s[i][cl] + c_h1r[j] * p1s[i][cl];
    }
    outs[n][cl] = acc;
  }
  __syncthreads();
  for (int idx = tid; idx < 32 * 104; idx += 256) {
    int ci = idx / 104, n = idx - ci * 104;
    int cg = c0 + ci;
    if (cg < kC) out[((size_t)b * kC + cg) * 104 + n] = outs[n][ci];
  }
}

extern "C" void kernel_launch(void* const* d_in, const int* in_sizes, int n_in,
                              void* d_out, int out_size, void* d_ws, size_t ws_size,
                              hipStream_t stream) {
  (void)in_sizes; (void)n_in; (void)out_size; (void)ws_size;
  const float* x = (const float*)d_in[0];
  auto inp = [&](int lvl, int j) { return (const float*)d_in[1 + 9 * lvl + j]; };

  float* outf = (float*)d_out;
  float* mout = outf + (size_t)kB * kC * 104;
  float* sout = mout + (size_t)kB * kC;

  float* Wp = (float*)d_ws;
  size_t off = 0;
  auto alloc = [&](size_t n) { float* p = Wp + off; off += (n + 63) & ~(size_t)63; return p; };

  // LO1+LO2 first & contiguous: later aliased as concatenated Q bf16 buffer (91 MB >= 88.1 MB)
  float* LO1 = alloc((size_t)kB * 365 * kC);
  float* LO2 = alloc((size_t)kB * 188 * kC);
  unsigned short* Xt1 = (unsigned short*)alloc((size_t)kB * kCp * 384 / 2);
  unsigned short* Xt2 = (unsigned short*)alloc((size_t)kB * kCp * 256 / 2);
  unsigned short* Xt0 = (unsigned short*)alloc((size_t)kB * kCp * 128 / 2);
  unsigned short* Xt3 = (unsigned short*)alloc((size_t)kB * kCp * 128 / 2);
  unsigned short* KbfAll = (unsigned short*)alloc((size_t)kB * kCp * 896 / 2);
  unsigned short* Wpv[8];
  for (int i = 0; i < 8; ++i)
    Wpv[i] = (unsigned short*)alloc((size_t)384 * 384 / 2);
  float* wgtAll = alloc((size_t)kB * (99 + 365 + 188 + 99));
  float* M0 = alloc((size_t)kB * 99);  float* M1 = alloc((size_t)kB * 365);
  float* M2 = alloc((size_t)kB * 188); float* M3 = alloc((size_t)kB * 99);
  float* S0 = alloc((size_t)kC * 22);  float* S1 = alloc((size_t)kC * 57);
  float* S2 = alloc((size_t)kC * 34);  float* S3 = alloc((size_t)kC * 22);
  float* P0 = alloc((size_t)kB * 22 * kC); float* P1 = alloc((size_t)kB * 57 * kC);
  float* P2 = alloc((size_t)kB * 34 * kC); float* P3 = alloc((size_t)kB * 22 * kC);
  float* ps   = alloc((size_t)kB * 8 * kC);
  float* ps2  = alloc((size_t)kB * 8 * kC);
  float* meanw = alloc((size_t)kB * kC);
  float* invw  = alloc((size_t)kB * kC);
  unsigned short* QbfAll = (unsigned short*)LO1;   // alias over LO1+LO2 (dead before qk_all)

  const int Lc[4]  = {99, 365, 188, 99};
  const int Lpv[4] = {128, 384, 256, 128};
  const int Ov[4]  = {22, 57, 34, 22};
  const int prefLp[4] = {0, 128, 512, 768};
  const int wOff[4] = {0, 99, 99 + 365, 99 + 365 + 188};
  unsigned short* Qlvl[4]; unsigned short* Klvl[4];
  for (int i = 0; i < 4; ++i) {
    Qlvl[i] = QbfAll + (size_t)kB * kCp * prefLp[i];
    Klvl[i] = KbfAll + (size_t)kB * kCp * prefLp[i];
  }
  const unsigned short* Xts[4] = {Xt0, Xt1, Xt2, Xt3};
  float* masks[4] = {M0, M1, M2, M3};
  float* smws[4]  = {S0, S1, S2, S3};
  float* preds[4] = {P0, P1, P2, P3};

  // 1) mean/std
  partial_ms_kernel<<<dim3(kB, 8, 3), 128, 0, stream>>>(x, ps, ps2);
  finalize_ms_kernel<<<(kB * kC + 255) / 256, 256, 0, stream>>>(ps, ps2, mout, sout, meanw, invw);

  // 2) fused DWT cascade
  dwt_fused_kernel<true, true, false><<<dim3(6, kCp / 64, kB), 256, 0, stream>>>(
      x, meanw, invw, LO1, nullptr, Xt1, kN0, 365, 384);
  dwt_fused_kernel<false, true, false><<<dim3(4, kCp / 64, kB), 256, 0, stream>>>(
      LO1, nullptr, nullptr, LO2, nullptr, Xt2, 365, 188, 256);
  dwt_fused_kernel<false, false, true><<<dim3(2, kCp / 64, kB), 256, 0, stream>>>(
      LO2, nullptr, nullptr, nullptr, Xt0, Xt3, 188, 99, 128);

  // 3) weight conversions (one launch) + wgt zero
  {
    WcArgs wa;
    for (int i = 0; i < 4; ++i) {
      wa.src[2 * i] = inp(i, 0); wa.src[2 * i + 1] = inp(i, 2);
      wa.dst[2 * i] = Wpv[2 * i]; wa.dst[2 * i + 1] = Wpv[2 * i + 1];
      wa.L[2 * i] = wa.L[2 * i + 1] = Lc[i];
      wa.Lp[2 * i] = wa.Lp[2 * i + 1] = Lpv[i];
    }
    wconv_all_kernel<<<dim3(576, 8), 256, 0, stream>>>(wa);
  }
  hipMemsetAsync(wgtAll, 0, (size_t)kB * (99 + 365 + 188 + 99) * sizeof(float), stream);

  // 4) all-level fused Q+K projections (one launch; runs after dwt3 so LO1/LO2 alias is safe)
  {
    QKAllArgs qa;
    for (int i = 0; i < 4; ++i) {
      qa.W[2 * i] = Wpv[2 * i]; qa.W[2 * i + 1] = Wpv[2 * i + 1];
      qa.bias[2 * i] = inp(i, 1); qa.bias[2 * i + 1] = inp(i, 3);
      qa.Y[2 * i] = Qlvl[i]; qa.Y[2 * i + 1] = Klvl[i];
      qa.Xt[i] = Xts[i]; qa.Lp[i] = Lpv[i]; qa.L[i] = Lc[i];
    }
    qa.yOff[0] = 0; qa.yOff[1] = 1; qa.yOff[2] = 4; qa.yOff[3] = 6;  // p-tiles: 1,3,2,1
    qk_all_kernel<<<dim3(kCp / 128, 7, kB), 512, 0, stream>>>(qa);
  }

  // 5) all-level scores (one launch, 1D grid + XCD swizzle)
  {
    ScAllArgs sa;
    for (int i = 0; i < 4; ++i) {
      sa.Q[i] = Qlvl[i]; sa.K[i] = Klvl[i];
      sa.wgt[i] = wgtAll + (size_t)kB * wOff[i];
      sa.Lp[i] = Lpv[i]; sa.L[i] = Lc[i];
      sa.scale[i] = 1.0f / sqrtf((float)Lc[i]);
    }
    sa.tOff[0] = 0; sa.tOff[1] = 1; sa.tOff[2] = 10; sa.tOff[3] = 14;  // 1,9,4,1 tiles
    scores_all_kernel<<<15 * kB, 256, 0, stream>>>(sa);
  }

  // 6) window masks + channel softmax (merged)
  {
    WinIwArgs wa;
    for (int i = 0; i < 4; ++i) {
      wa.wgt[i] = wgtAll + (size_t)kB * wOff[i];
      wa.al[i] = inp(i, 7); wa.be[i] = inp(i, 8);
      wa.mask[i] = masks[i]; wa.L[i] = Lc[i];
      wa.iw[i] = inp(i, 6); wa.sm[i] = smws[i]; wa.O[i] = Ov[i];
    }
    winiw_kernel<<<512 + 135, 64, 0, stream>>>(wa);
  }

  // 7) all-level pred projections (one launch)
  {
    PredAllArgs pa;
    for (int i = 0; i < 4; ++i) {
      pa.Xt[i] = Xts[i]; pa.PW[i] = inp(i, 4); pa.PB[i] = inp(i, 5);
      pa.MK[i] = masks[i]; pa.SM[i] = smws[i]; pa.OUT[i] = preds[i];
      pa.L[i] = Lc[i]; pa.Lp[i] = Lpv[i]; pa.O[i] = Ov[i];
    }
    pred_all_kernel<<<dim3(kCp / 128, 4, kB), 256, 0, stream>>>(pa);
  }

  // 8) fused reconstruction + transpose
  sfb_fused_kernel<<<dim3(11, kB), 256, 0, stream>>>(P0, P1, P2, P3, outf);
}

// Round 7
// 761.075 us; speedup vs baseline: 1.0265x; 1.0196x over previous
//
#include <hip/hip_runtime.h>
#include <hip/hip_bf16.h>
#include <math.h>

namespace {
constexpr int kB  = 128;
constexpr int kC  = 321;
constexpr int kN0 = 720;
constexpr int kCp = 384;   // padded channel dim for MFMA
}

typedef __attribute__((ext_vector_type(8))) short short8;
typedef __attribute__((ext_vector_type(4))) float floatx4;

// db6 analysis filters (H0 = lowpass, H1 = qmf highpass), and reversed copies
__constant__ float c_h0[12] = {
  0.11154074335008017f, 0.4946238903983854f, 0.7511339080215775f,
  0.3152503517092432f, -0.22626469396516913f, -0.12976686756709563f,
  0.09750160558707936f, 0.02752286553001629f, -0.031582039318031156f,
  0.0005538422009938016f, 0.004777257511010651f, -0.00107730108499558f};
__constant__ float c_h1[12] = {
  -0.00107730108499558f, -0.004777257511010651f, 0.0005538422009938016f,
  0.031582039318031156f, 0.02752286553001629f, -0.09750160558707936f,
  -0.12976686756709563f, 0.22626469396516913f, 0.3152503517092432f,
  -0.7511339080215775f, 0.4946238903983854f, -0.11154074335008017f};
__constant__ float c_h0r[12] = {
  -0.00107730108499558f, 0.004777257511010651f, 0.0005538422009938016f,
  -0.031582039318031156f, 0.02752286553001629f, 0.09750160558707936f,
  -0.12976686756709563f, -0.22626469396516913f, 0.3152503517092432f,
  0.7511339080215775f, 0.4946238903983854f, 0.11154074335008017f};
__constant__ float c_h1r[12] = {
  -0.11154074335008017f, 0.4946238903983854f, -0.7511339080215775f,
  0.3152503517092432f, 0.22626469396516913f, -0.12976686756709563f,
  -0.09750160558707936f, 0.02752286553001629f, 0.031582039318031156f,
  0.0005538422009938016f, -0.004777257511010651f, -0.00107730108499558f};

__device__ __forceinline__ float fast_tanh(float x) {
  float e = __expf(2.f * x);
  return 1.f - 2.f / (e + 1.f);
}
__device__ __forceinline__ unsigned short f2b(float f) {
  __hip_bfloat16 h = __float2bfloat16(f);
  return __builtin_bit_cast(unsigned short, h);
}

// async global->LDS, 16B per lane; LDS dest = wave-uniform base + lane*16
__device__ __forceinline__ void gload16(const unsigned short* g, short* l) {
  __builtin_amdgcn_global_load_lds(
      (const __attribute__((address_space(1))) unsigned int*)g,
      (__attribute__((address_space(3))) unsigned int*)l, 16, 0, 0);
}

// ---------- mean/std over time axis: 8 chunks x 90 t, unrolled for MLP ----------
__global__ void __launch_bounds__(128) partial_ms_kernel(
    const float* __restrict__ x, float* __restrict__ ps, float* __restrict__ ps2) {
  int b = blockIdx.x, chunk = blockIdx.y;
  int c = blockIdx.z * 128 + threadIdx.x;
  if (c >= kC) return;
  const float* xb = x + (size_t)b * kN0 * kC + c;
  int t0 = chunk * 90;
  float s = 0.f, s2 = 0.f;
#pragma unroll 15
  for (int i = 0; i < 90; ++i) {
    float v = xb[(size_t)(t0 + i) * kC];
    s += v; s2 += v * v;
  }
  ps [(b * 8 + chunk) * kC + c] = s;
  ps2[(b * 8 + chunk) * kC + c] = s2;
}

__global__ void __launch_bounds__(256) finalize_ms_kernel(
    const float* __restrict__ ps, const float* __restrict__ ps2,
    float* __restrict__ mout, float* __restrict__ sout,
    float* __restrict__ meanw, float* __restrict__ invw) {
  int i = blockIdx.x * 256 + threadIdx.x;
  if (i >= kB * kC) return;
  int b = i / kC, c = i - b * kC;
  float s = 0.f, s2 = 0.f;
#pragma unroll
  for (int k = 0; k < 8; ++k) { s += ps[(b * 8 + k) * kC + c]; s2 += ps2[(b * 8 + k) * kC + c]; }
  float mean = s * (1.f / (float)kN0);
  float var = s2 * (1.f / (float)kN0) - mean * mean;
  float sd = sqrtf(var + 1e-5f);
  mout[i] = mean; sout[i] = sd;
  meanw[i] = mean; invw[i] = 1.f / sd;
}

__device__ __forceinline__ int sym_reflect(int t, int N) {
  t = (t < 0) ? (-1 - t) : t;
  t = (t >= N) ? (2 * N - 1 - t) : t;
  return t;
}

// ---------- fused tiled DWT level ----------
template <bool NORM, bool LO_F32, bool LO_BF16>
__global__ void __launch_bounds__(256) dwt_fused_kernel(
    const float* __restrict__ in, const float* __restrict__ meanw,
    const float* __restrict__ invw, float* __restrict__ loF,
    unsigned short* __restrict__ loB, unsigned short* __restrict__ hiB,
    int N, int L, int Lp) {
  __shared__ float xs[138][64];
  __shared__ unsigned short los[64][72];
  __shared__ unsigned short his[64][72];
  const int b = blockIdx.z;
  const int n0 = blockIdx.x * 64, c0 = blockIdx.y * 64;
  const int tid = threadIdx.x;
  const int cl = tid & 63, wv = tid >> 6;
  const int c = c0 + cl;
  const int t0 = 2 * n0 - 10;
  const float* ib = in + (size_t)b * N * kC;
  float mean = 0.f, inv = 1.f;
  if (NORM && c < kC) { mean = meanw[b * kC + c]; inv = invw[b * kC + c]; }
  for (int r = wv; r < 138; r += 4) {
    int t = sym_reflect(t0 + r, N);
    float v = (c < kC) ? ib[(size_t)t * kC + c] : 0.f;
    if (NORM) v = (v - mean) * inv;
    xs[r][cl] = v;
  }
  __syncthreads();
#pragma unroll 4
  for (int k = 0; k < 16; ++k) {
    int nl = wv + 4 * k;
    int n = n0 + nl;
    float a0 = 0.f, a1 = 0.f;
    int base = 2 * nl;
#pragma unroll
    for (int j = 0; j < 12; ++j) {
      float v = xs[base + j][cl];
      a0 += v * c_h0[j]; a1 += v * c_h1[j];
    }
    bool valid = (n < L) && (c < kC);
    if (LO_F32 && valid) loF[((size_t)b * L + n) * kC + c] = a0;
    if (LO_BF16) los[cl][nl] = f2b(valid ? a0 : 0.f);
    his[cl][nl] = f2b(valid ? a1 : 0.f);
  }
  __syncthreads();
  int row = tid >> 2, part = tid & 3;
  size_t dst = ((size_t)b * kCp + c0 + row) * Lp + n0 + part * 16;
  *(uint4*)(hiB + dst)     = *(const uint4*)&his[row][part * 16];
  *(uint4*)(hiB + dst + 8) = *(const uint4*)&his[row][part * 16 + 8];
  if (LO_BF16) {
    *(uint4*)(loB + dst)     = *(const uint4*)&los[row][part * 16];
    *(uint4*)(loB + dst + 8) = *(const uint4*)&los[row][part * 16 + 8];
  }
}

// ---------- all-level weight fp32 [L][L] -> bf16 [Lp][Lp] zero-padded ----------
struct WcArgs { const float* src[8]; unsigned short* dst[8]; int L[8]; int Lp[8]; };
__global__ void __launch_bounds__(256) wconv_all_kernel(WcArgs a) {
  int lvl = blockIdx.y;
  int Lp = a.Lp[lvl], L = a.L[lvl];
  int i = blockIdx.x * 256 + threadIdx.x;
  if (i >= Lp * Lp) return;
  int p = i / Lp, l = i - p * Lp;
  a.dst[lvl][i] = f2b((p < L && l < L) ? a.src[lvl][(size_t)p * L + l] : 0.f);
}

// ---------- ALL levels Q+K projections fused, K-step 32, dbuf 40 KB.
// Chunk-XOR swizzle (16B granule, key (row>>1)&3): source inverse-swizzled,
// LDS dest linear (global_load_lds), reads use per-lane constant phys chunk.
// K-loop trimmed to ceil(L/32) steps (W cols and X cols >= L are zeros).
// Epilogue: LDS bounce -> uint4 coalesced stores, PAD ROWS (p>=L) SKIPPED
// (consumers: scores predicates l<L; K pad-s products are discarded). ----------
struct QKAllArgs {
  const unsigned short* W[8];     // [2*lvl+sel]
  const unsigned short* Xt[4];
  const float* bias[8];
  unsigned short* Y[8];
  int Lp[4], L[4], yOff[4];       // yOff = {0,1,4,6} (p-tiles per level: 1,3,2,1)
};
__global__ void __launch_bounds__(512, 8) qk_all_kernel(QKAllArgs a) {
  const int y = blockIdx.y;
  const int lvl = (y >= a.yOff[1]) + (y >= a.yOff[2]) + (y >= a.yOff[3]);
  const int Lp = a.Lp[lvl], L = a.L[lvl];
  const int pBase = (y - a.yOff[lvl]) * 128;
  const unsigned short* W0 = a.W[2 * lvl]     + (size_t)pBase * Lp;
  const unsigned short* W1 = a.W[2 * lvl + 1] + (size_t)pBase * Lp;
  const int b = blockIdx.z;
  const int cBase = blockIdx.x * 64;
  const int tid = threadIdx.x;
  const int ln = tid & 63, w = tid >> 6;
  __shared__ short smem[2 * 320 * 32];   // 40 KB: 2 phases x (Aq128|Ak128|Bs64) x 32
  floatx4 acc[2][4] = {};                // [out s][ni]
  const unsigned short* Xb = a.Xt[lvl] + ((size_t)b * kCp + cBase) * Lp;
  // staging: each gload16 covers 16 rows of 64 B; lane -> row o*16+(ln>>2),
  // physical chunk ln&3; source column = logical chunk = (phys - ((row>>1)&3))&3
  const int lr = ln >> 2;
  const int kOfs = ((((ln & 3) - ((ln >> 3) & 3)) & 3)) * 8;   // shorts
  // 20 loads/phase over 8 waves: waves 0-3 do 3, waves 4-7 do 2
  const int nld = (w < 4) ? 3 : 2;
  const int ow0 = (w < 4) ? w * 3 : 12 + (w - 4) * 2;
  const unsigned short* srcs[3];
#pragma unroll
  for (int i = 0; i < 3; ++i) {
    int o = (i < nld) ? (ow0 + i) : ow0;
    int rr = o * 16 + lr;
    const unsigned short* s = (o < 8)  ? (W0 + (size_t)rr * Lp)
                            : (o < 16) ? (W1 + (size_t)(rr - 128) * Lp)
                                       : (Xb + (size_t)(rr - 256) * Lp);
    srcs[i] = s + kOfs;
  }
  // fragment read: physical chunk = ((ln>>4) + ((ln>>1)&3)) & 3
  const int sc = ((((ln >> 4) + ((ln >> 1) & 3)) & 3)) * 8;
  const int nt = (L + 31) >> 5;          // trimmed: trailing l-chunks are zero
  // prologue: stage K-step 0 into phase 0
#pragma unroll
  for (int i = 0; i < 3; ++i)
    if (i < nld) gload16(srcs[i], &smem[(ow0 + i) * 512]);
  __syncthreads();
  for (int kt = 0; kt < nt; ++kt) {
    if (kt + 1 < nt) {
      const int phn = ((kt + 1) & 1) * 10240;
#pragma unroll
      for (int i = 0; i < 3; ++i)
        if (i < nld) { srcs[i] += 32; gload16(srcs[i], &smem[phn + (ow0 + i) * 512]); }
    }
    const int ph = (kt & 1) * 10240;
    const int ar = (w * 16 + (ln & 15)) * 32 + sc;
    short8 aq = *(const short8*)&smem[ph + ar];
    short8 ak = *(const short8*)&smem[ph + 4096 + ar];
    short8 bv[4];
#pragma unroll
    for (int ni = 0; ni < 4; ++ni)
      bv[ni] = *(const short8*)&smem[ph + 8192 + (ni * 16 + (ln & 15)) * 32 + sc];
#pragma unroll
    for (int ni = 0; ni < 4; ++ni) {
      acc[0][ni] = __builtin_amdgcn_mfma_f32_16x16x32_bf16(aq, bv[ni], acc[0][ni], 0, 0, 0);
      acc[1][ni] = __builtin_amdgcn_mfma_f32_16x16x32_bf16(ak, bv[ni], acc[1][ni], 0, 0, 0);
    }
    __syncthreads();
  }
  // epilogue via LDS bounce (smem free after final barrier).
  // K needs c<kC zeroing (pad-c kills pad products in scores).
  // Pad rows (p>=L) are NOT stored: scores predicates l<L, masks s<L.
  short* yq = smem;
  short* yk = smem + 8192;
#pragma unroll
  for (int s = 0; s < 2; ++s) {
    const float* bias = a.bias[2 * lvl + s];
    short* dstL = s ? yk : yq;
#pragma unroll
    for (int r = 0; r < 4; ++r) {
      int pl = w * 16 + (ln >> 4) * 4 + r;
      int p = pBase + pl;
      bool pv = (p < L);
      float bvf = pv ? bias[p] : 0.f;
#pragma unroll
      for (int ni = 0; ni < 4; ++ni) {
        int cl = ni * 16 + (ln & 15);
        float v = fast_tanh(acc[s][ni][r] + bvf);
        if (s == 1 && cBase + cl >= kC) v = 0.f;
        dstL[pl * 64 + (cl ^ ((pl & 7) << 3))] = (short)f2b(v);
      }
    }
  }
  __syncthreads();
#pragma unroll
  for (int s = 0; s < 2; ++s) {
    unsigned short* Yd = a.Y[2 * lvl + s];
    const short* srcL = s ? yk : yq;
#pragma unroll
    for (int j = 0; j < 2; ++j) {
      int idx = tid * 2 + j;           // 0..1023
      int row = idx >> 3;              // 0..127
      if (pBase + row >= L) continue;  // skip pad-row stores
      int ch = idx & 7;                // logical 8-short chunk
      int pch = ch ^ (row & 7);        // physical chunk
      uint4 vv = *(const uint4*)&srcL[row * 64 + pch * 8];
      *(uint4*)(Yd + ((size_t)b * Lp + pBase + row) * kCp + cBase + ch * 8) = vv;
    }
  }
}

// ---------- ALL levels scores, K-step 32, dbuf 32 KB, 512 thr.
// 1D grid + bijective XCD swizzle (1920 blocks, 240/XCD). Same chunk-XOR
// swizzle as qk. c-loop trimmed to ceil(kC/32)=11 steps (K pad-c is zero).
// Reduction predicated on l<L (Q pad rows are no longer written). ----------
struct ScAllArgs {
  const unsigned short* Q[4]; const unsigned short* K[4];
  float* wgt[4];
  int Lp[4], L[4], tOff[4];     // tOff = {0,1,10,14}
  float scale[4];
};
__global__ void __launch_bounds__(512, 8) scores_all_kernel(ScAllArgs a) {
  const int bid = blockIdx.x;                 // 0..1919
  const int wg = (bid & 7) * 240 + (bid >> 3);
  const int t = wg % 15;
  const int b = wg / 15;
  const int lvl = (t >= a.tOff[1]) + (t >= a.tOff[2]) + (t >= a.tOff[3]);
  const int rel = t - a.tOff[lvl];
  const int Lp = a.Lp[lvl], L = a.L[lvl];
  const int pt = Lp >> 7;
  const int sBase = (rel % pt) * 128;
  const int lBase = (rel / pt) * 128;
  const int tid = threadIdx.x;
  const int ln = tid & 63, w = tid >> 6;
  const int wm = w & 3, wn = w >> 2;     // wave tile 32l x 64s
  __shared__ short smem[2 * 256 * 32];   // 32 KB: 2 phases x (Q128|K128) x 32
  __shared__ float red[128];
  floatx4 acc[2][4] = {};
  const unsigned short* Qp = a.Q[lvl] + ((size_t)b * Lp + lBase) * kCp;
  const unsigned short* Kp = a.K[lvl] + ((size_t)b * Lp + sBase) * kCp;
  const int lr = ln >> 2;
  const int kOfs = ((((ln & 3) - ((ln >> 3) & 3)) & 3)) * 8;
  const unsigned short* srcs[2];
#pragma unroll
  for (int i = 0; i < 2; ++i) {
    int o = w * 2 + i;                   // 0..15
    int rr = o * 16 + lr;                // 0..255
    srcs[i] = ((o < 8) ? (Qp + (size_t)rr * kCp)
                       : (Kp + (size_t)(rr - 128) * kCp)) + kOfs;
  }
  const int sc = ((((ln >> 4) + ((ln >> 1) & 3)) & 3)) * 8;
#pragma unroll
  for (int i = 0; i < 2; ++i) gload16(srcs[i], &smem[(w * 2 + i) * 512]);
  if (tid < 128) red[tid] = 0.f;
  __syncthreads();
  const int nt = (kC + 31) >> 5;   // 11: c in [352,384) is all-zero K
  for (int kt = 0; kt < nt; ++kt) {
    if (kt + 1 < nt) {
      const int phn = ((kt + 1) & 1) * 8192;
#pragma unroll
      for (int i = 0; i < 2; ++i) { srcs[i] += 32; gload16(srcs[i], &smem[phn + (w * 2 + i) * 512]); }
    }
    const int ph = (kt & 1) * 8192;
    short8 av[2], bv[4];
#pragma unroll
    for (int mi = 0; mi < 2; ++mi)
      av[mi] = *(const short8*)&smem[ph + (wm * 32 + mi * 16 + (ln & 15)) * 32 + sc];
#pragma unroll
    for (int ni = 0; ni < 4; ++ni)
      bv[ni] = *(const short8*)&smem[ph + 4096 + (wn * 64 + ni * 16 + (ln & 15)) * 32 + sc];
#pragma unroll
    for (int mi = 0; mi < 2; ++mi)
#pragma unroll
      for (int ni = 0; ni < 4; ++ni)
        acc[mi][ni] = __builtin_amdgcn_mfma_f32_16x16x32_bf16(av[mi], bv[ni], acc[mi][ni], 0, 0, 0);
    __syncthreads();
  }
  const float scale = a.scale[lvl];
#pragma unroll
  for (int ni = 0; ni < 4; ++ni) {
    float p = 0.f;
#pragma unroll
    for (int mi = 0; mi < 2; ++mi)
#pragma unroll
      for (int r = 0; r < 4; ++r) {
        int l = lBase + wm * 32 + mi * 16 + (ln >> 4) * 4 + r;
        if (l < L) p += fast_tanh(acc[mi][ni][r] * scale);
      }
    p += __shfl_xor(p, 16);
    p += __shfl_xor(p, 32);
    if ((ln & 48) == 0) atomicAdd(&red[wn * 64 + ni * 16 + (ln & 15)], p);
  }
  __syncthreads();
  if (tid < 128) {
    int s = sBase + tid;
    if (s < L) atomicAdd(&a.wgt[lvl][(size_t)b * L + s], red[tid]);
  }
}

// ---------- merged window mask + iw softmax (one launch) ----------
struct WinIwArgs {
  const float* wgt[4]; const float* al[4]; const float* be[4];
  float* mask[4]; int L[4];
  const float* iw[4]; float* sm[4]; int O[4];
};
__global__ void __launch_bounds__(64) winiw_kernel(WinIwArgs a) {
  int bx = blockIdx.x;
  int lane = threadIdx.x;
  if (bx < 512) {
    int lvl = bx >> 7, b = bx & 127;
    int L = a.L[lvl];
    const float* wgt = a.wgt[lvl] + (size_t)b * L;
    float al = a.al[lvl][0], be = a.be[lvl][0];
    float invL = 1.f / (float)L;
    int chunk = (L + 63) >> 6;            // <= 6
    int s0 = lane * chunk;
    float v[6];
    float csum = 0.f;
    for (int i = chunk - 1; i >= 0; --i) {
      int s = s0 + i;
      float xv = (s < L) ? wgt[s] * invL : 0.f;
      csum += xv; v[i] = csum;
    }
    float tot = csum;
    for (int o = 1; o < 64; o <<= 1) {
      float t = __shfl_down(tot, o);
      if (lane + o < 64) tot += t;
    }
    float excl = tot - csum;
    float m = -1e30f;
    for (int i = 0; i < chunk; ++i)
      if (s0 + i < L) m = fmaxf(m, al * (v[i] + excl));
    for (int o = 32; o; o >>= 1) m = fmaxf(m, __shfl_xor(m, o));
    float sum = 0.f, num = 0.f;
    for (int i = 0; i < chunk; ++i) {
      int s = s0 + i;
      if (s < L) { float e = __expf(al * (v[i] + excl) - m); sum += e; num += e * (float)s; }
    }
    for (int o = 32; o; o >>= 1) { sum += __shfl_xor(sum, o); num += __shfl_xor(num, o); }
    float win = num / sum;
    float* mk = a.mask[lvl] + (size_t)b * L;
    for (int i = 0; i < chunk; ++i) {
      int s = s0 + i;
      if (s < L) mk[s] = 1.f / (1.f + __expf(-((float)s - win) * be));
    }
  } else {
    int x = bx - 512;
    int lvl, o;
    if (x < 22) { lvl = 0; o = x; }
    else if (x < 79) { lvl = 1; o = x - 22; }
    else if (x < 113) { lvl = 2; o = x - 79; }
    else { lvl = 3; o = x - 113; }
    int O = a.O[lvl];
    const float* iw = a.iw[lvl];
    float m = -1e30f;
    for (int c = lane; c < kC; c += 64) m = fmaxf(m, iw[c * O + o]);
    for (int k = 32; k; k >>= 1) m = fmaxf(m, __shfl_xor(m, k));
    float sum = 0.f;
    for (int c = lane; c < kC; c += 64) sum += __expf(iw[c * O + o] - m);
    for (int k = 32; k; k >>= 1) sum += __shfl_xor(sum, k);
    float inv = 1.f / sum;
    for (int c = lane; c < kC; c += 64) a.sm[lvl][c * O + o] = __expf(iw[c * O + o] - m) * inv;
  }
}

// ---------- ALL levels pred via MFMA ----------
struct PredAllArgs {
  const unsigned short* Xt[4];
  const float* PW[4]; const float* PB[4]; const float* MK[4]; const float* SM[4];
  float* OUT[4];
  int L[4], Lp[4], O[4];
};
__global__ void __launch_bounds__(256) pred_all_kernel(PredAllArgs a) {
  const int lvl = blockIdx.y;
  const int L = a.L[lvl], Lp = a.Lp[lvl], O = a.O[lvl];
  const float* PW = a.PW[lvl];
  const int b = blockIdx.z;
  const int cBase = blockIdx.x * 128;
  const int tid = threadIdx.x;
  const int ln = tid & 63, w = tid >> 6;
  __shared__ short As[64 * 40];
  __shared__ short Bs[128 * 40];
  floatx4 acc[8] = {};
  const unsigned short* Xb = a.Xt[lvl] + ((size_t)b * kCp + cBase) * Lp;
  const float* mk = a.MK[lvl] + (size_t)b * L;
  for (int lc = 0; lc < Lp; lc += 32) {
    {
      int o = tid >> 2, j0 = (tid & 3) * 8;
      alignas(16) unsigned short tmp[8];
#pragma unroll
      for (int j = 0; j < 8; ++j) {
        int l = lc + j0 + j;
        float v = (o < O && l < L) ? PW[(size_t)o * L + l] * mk[l] : 0.f;
        tmp[j] = f2b(v);
      }
      *(uint4*)&As[o * 40 + j0] = *(const uint4*)tmp;
    }
#pragma unroll
    for (int q = 0; q < 2; ++q) {
      int ch = tid * 2 + q;
      int row = ch >> 2, pos = ch & 3;
      *(uint4*)(&Bs[row * 40 + pos * 8]) = *(const uint4*)(Xb + (size_t)row * Lp + lc + pos * 8);
    }
    __syncthreads();
    short8 av = *(const short8*)&As[(w * 16 + (ln & 15)) * 40 + (ln >> 4) * 8];
#pragma unroll
    for (int ni = 0; ni < 8; ++ni) {
      short8 bb = *(const short8*)&Bs[(ni * 16 + (ln & 15)) * 40 + (ln >> 4) * 8];
      acc[ni] = __builtin_amdgcn_mfma_f32_16x16x32_bf16(av, bb, acc[ni], 0, 0, 0);
    }
    __syncthreads();
  }
  const float negln = -logf(10000.f) / (float)O;
#pragma unroll
  for (int ni = 0; ni < 8; ++ni) {
    int c = cBase + ni * 16 + (ln & 15);
    if (c >= kC) continue;
#pragma unroll
    for (int r = 0; r < 4; ++r) {
      int o = w * 16 + (ln >> 4) * 4 + r;
      if (o >= O) continue;
      float dv = __expf(negln * (float)(2 * (o >> 1)));
      float ang = (float)c * dv;
      float pe = (o & 1) ? cosf(ang) : sinf(ang);
      a.OUT[lvl][((size_t)b * O + o) * kC + c] = a.SM[lvl][c * O + o] * (acc[ni][r] + a.PB[lvl][o] + pe);
    }
  }
}

// ---------- fused 3-stage synthesis + transpose: out[b][c][104] ----------
__global__ void __launch_bounds__(256) sfb_fused_kernel(
    const float* __restrict__ P0, const float* __restrict__ P1,
    const float* __restrict__ P2, const float* __restrict__ P3,
    float* __restrict__ out) {
  __shared__ float p0s[22][32], p3s[22][32], p2s[34][32], p1s[57][32];
  __shared__ float r1s[34][32], r2s[58][32];
  __shared__ float outs[104][33];
  int b = blockIdx.y, c0 = blockIdx.x * 32;
  int tid = threadIdx.x;
  int cl = tid & 31, r = tid >> 5;
  int c = c0 + cl;
  bool cv = c < kC;
  for (int o = r; o < 22; o += 8) {
    p0s[o][cl] = cv ? P0[((size_t)b * 22 + o) * kC + c] : 0.f;
    p3s[o][cl] = cv ? P3[((size_t)b * 22 + o) * kC + c] : 0.f;
  }
  for (int o = r; o < 34; o += 8) p2s[o][cl] = cv ? P2[((size_t)b * 34 + o) * kC + c] : 0.f;
  for (int o = r; o < 57; o += 8) p1s[o][cl] = cv ? P1[((size_t)b * 57 + o) * kC + c] : 0.f;
  __syncthreads();
  for (int n = r; n < 34; n += 8) {
    float acc = 0.f;
#pragma unroll
    for (int j = 0; j < 12; ++j) {
      int m = n + j - 1;
      if (m < 0 || (m & 1)) continue;
      int i = m >> 1;
      if (i >= 22) continue;
      acc += c_h0r[j] * p0s[i][cl] + c_h1r[j] * p3s[i][cl];
    }
    r1s[n][cl] = acc;
  }
  __syncthreads();
  for (int n = r; n < 58; n += 8) {
    float acc = 0.f;
#pragma unroll
    for (int j = 0; j < 12; ++j) {
      int m = n + j - 1;
      if (m < 0 || (m & 1)) continue;
      int i = m >> 1;
      if (i >= 34) continue;
      acc += c_h0r[j] * r1s[i][cl] + c_h1r[j] * p2s[i][cl];
    }
    r2s[n][cl] = acc;
  }
  __syncthreads();
  for (int n = r; n < 104; n += 8) {
    float acc = 0.f;
#pragma unroll
    for (int j = 0; j < 12; ++j) {
      int m = n + j - 1;
      if (m < 0 || (m & 1)) continue;
      int i = m >> 1;
      if (i >= 57) continue;
      acc += c_h0r[j] * r2s[i][cl] + c_h1r[j] * p1s[i][cl];
    }
    outs[n][cl] = acc;
  }
  __syncthreads();
  for (int idx = tid; idx < 32 * 104; idx += 256) {
    int ci = idx / 104, n = idx - ci * 104;
    int cg = c0 + ci;
    if (cg < kC) out[((size_t)b * kC + cg) * 104 + n] = outs[n][ci];
  }
}

extern "C" void kernel_launch(void* const* d_in, const int* in_sizes, int n_in,
                              void* d_out, int out_size, void* d_ws, size_t ws_size,
                              hipStream_t stream) {
  (void)in_sizes; (void)n_in; (void)out_size; (void)ws_size;
  const float* x = (const float*)d_in[0];
  auto inp = [&](int lvl, int j) { return (const float*)d_in[1 + 9 * lvl + j]; };

  float* outf = (float*)d_out;
  float* mout = outf + (size_t)kB * kC * 104;
  float* sout = mout + (size_t)kB * kC;

  float* Wp = (float*)d_ws;
  size_t off = 0;
  auto alloc = [&](size_t n) { float* p = Wp + off; off += (n + 63) & ~(size_t)63; return p; };

  // LO1+LO2 first & contiguous: later aliased as concatenated Q bf16 buffer (91 MB >= 88.1 MB)
  float* LO1 = alloc((size_t)kB * 365 * kC);
  float* LO2 = alloc((size_t)kB * 188 * kC);
  unsigned short* Xt1 = (unsigned short*)alloc((size_t)kB * kCp * 384 / 2);
  unsigned short* Xt2 = (unsigned short*)alloc((size_t)kB * kCp * 256 / 2);
  unsigned short* Xt0 = (unsigned short*)alloc((size_t)kB * kCp * 128 / 2);
  unsigned short* Xt3 = (unsigned short*)alloc((size_t)kB * kCp * 128 / 2);
  unsigned short* KbfAll = (unsigned short*)alloc((size_t)kB * kCp * 896 / 2);
  unsigned short* Wpv[8];
  for (int i = 0; i < 8; ++i)
    Wpv[i] = (unsigned short*)alloc((size_t)384 * 384 / 2);
  float* wgtAll = alloc((size_t)kB * (99 + 365 + 188 + 99));
  float* M0 = alloc((size_t)kB * 99);  float* M1 = alloc((size_t)kB * 365);
  float* M2 = alloc((size_t)kB * 188); float* M3 = alloc((size_t)kB * 99);
  float* S0 = alloc((size_t)kC * 22);  float* S1 = alloc((size_t)kC * 57);
  float* S2 = alloc((size_t)kC * 34);  float* S3 = alloc((size_t)kC * 22);
  float* P0 = alloc((size_t)kB * 22 * kC); float* P1 = alloc((size_t)kB * 57 * kC);
  float* P2 = alloc((size_t)kB * 34 * kC); float* P3 = alloc((size_t)kB * 22 * kC);
  float* ps   = alloc((size_t)kB * 8 * kC);
  float* ps2  = alloc((size_t)kB * 8 * kC);
  float* meanw = alloc((size_t)kB * kC);
  float* invw  = alloc((size_t)kB * kC);
  unsigned short* QbfAll = (unsigned short*)LO1;   // alias over LO1+LO2 (dead before qk_all)

  const int Lc[4]  = {99, 365, 188, 99};
  const int Lpv[4] = {128, 384, 256, 128};
  const int Ov[4]  = {22, 57, 34, 22};
  const int prefLp[4] = {0, 128, 512, 768};
  const int wOff[4] = {0, 99, 99 + 365, 99 + 365 + 188};
  unsigned short* Qlvl[4]; unsigned short* Klvl[4];
  for (int i = 0; i < 4; ++i) {
    Qlvl[i] = QbfAll + (size_t)kB * kCp * prefLp[i];
    Klvl[i] = KbfAll + (size_t)kB * kCp * prefLp[i];
  }
  const unsigned short* Xts[4] = {Xt0, Xt1, Xt2, Xt3};
  float* masks[4] = {M0, M1, M2, M3};
  float* smws[4]  = {S0, S1, S2, S3};
  float* preds[4] = {P0, P1, P2, P3};

  // 1) mean/std
  partial_ms_kernel<<<dim3(kB, 8, 3), 128, 0, stream>>>(x, ps, ps2);
  finalize_ms_kernel<<<(kB * kC + 255) / 256, 256, 0, stream>>>(ps, ps2, mout, sout, meanw, invw);

  // 2) fused DWT cascade
  dwt_fused_kernel<true, true, false><<<dim3(6, kCp / 64, kB), 256, 0, stream>>>(
      x, meanw, invw, LO1, nullptr, Xt1, kN0, 365, 384);
  dwt_fused_kernel<false, true, false><<<dim3(4, kCp / 64, kB), 256, 0, stream>>>(
      LO1, nullptr, nullptr, LO2, nullptr, Xt2, 365, 188, 256);
  dwt_fused_kernel<false, false, true><<<dim3(2, kCp / 64, kB), 256, 0, stream>>>(
      LO2, nullptr, nullptr, nullptr, Xt0, Xt3, 188, 99, 128);

  // 3) weight conversions (one launch) + wgt zero
  {
    WcArgs wa;
    for (int i = 0; i < 4; ++i) {
      wa.src[2 * i] = inp(i, 0); wa.src[2 * i + 1] = inp(i, 2);
      wa.dst[2 * i] = Wpv[2 * i]; wa.dst[2 * i + 1] = Wpv[2 * i + 1];
      wa.L[2 * i] = wa.L[2 * i + 1] = Lc[i];
      wa.Lp[2 * i] = wa.Lp[2 * i + 1] = Lpv[i];
    }
    wconv_all_kernel<<<dim3(576, 8), 256, 0, stream>>>(wa);
  }
  hipMemsetAsync(wgtAll, 0, (size_t)kB * (99 + 365 + 188 + 99) * sizeof(float), stream);

  // 4) all-level fused Q+K projections (one launch; runs after dwt3 so LO1/LO2 alias is safe)
  {
    QKAllArgs qa;
    for (int i = 0; i < 4; ++i) {
      qa.W[2 * i] = Wpv[2 * i]; qa.W[2 * i + 1] = Wpv[2 * i + 1];
      qa.bias[2 * i] = inp(i, 1); qa.bias[2 * i + 1] = inp(i, 3);
      qa.Y[2 * i] = Qlvl[i]; qa.Y[2 * i + 1] = Klvl[i];
      qa.Xt[i] = Xts[i]; qa.Lp[i] = Lpv[i]; qa.L[i] = Lc[i];
    }
    qa.yOff[0] = 0; qa.yOff[1] = 1; qa.yOff[2] = 4; qa.yOff[3] = 6;  // p-tiles: 1,3,2,1
    qk_all_kernel<<<dim3(kCp / 64, 7, kB), 512, 0, stream>>>(qa);
  }

  // 5) all-level scores (one launch, 1D grid + XCD swizzle)
  {
    ScAllArgs sa;
    for (int i = 0; i < 4; ++i) {
      sa.Q[i] = Qlvl[i]; sa.K[i] = Klvl[i];
      sa.wgt[i] = wgtAll + (size_t)kB * wOff[i];
      sa.Lp[i] = Lpv[i]; sa.L[i] = Lc[i];
      sa.scale[i] = 1.0f / sqrtf((float)Lc[i]);
    }
    sa.tOff[0] = 0; sa.tOff[1] = 1; sa.tOff[2] = 10; sa.tOff[3] = 14;  // 1,9,4,1 tiles
    scores_all_kernel<<<15 * kB, 512, 0, stream>>>(sa);
  }

  // 6) window masks + channel softmax (merged)
  {
    WinIwArgs wa;
    for (int i = 0; i < 4; ++i) {
      wa.wgt[i] = wgtAll + (size_t)kB * wOff[i];
      wa.al[i] = inp(i, 7); wa.be[i] = inp(i, 8);
      wa.mask[i] = masks[i]; wa.L[i] = Lc[i];
      wa.iw[i] = inp(i, 6); wa.sm[i] = smws[i]; wa.O[i] = Ov[i];
    }
    winiw_kernel<<<512 + 135, 64, 0, stream>>>(wa);
  }

  // 7) all-level pred projections (one launch)
  {
    PredAllArgs pa;
    for (int i = 0; i < 4; ++i) {
      pa.Xt[i] = Xts[i]; pa.PW[i] = inp(i, 4); pa.PB[i] = inp(i, 5);
      pa.MK[i] = masks[i]; pa.SM[i] = smws[i]; pa.OUT[i] = preds[i];
      pa.L[i] = Lc[i]; pa.Lp[i] = Lpv[i]; pa.O[i] = Ov[i];
    }
    pred_all_kernel<<<dim3(kCp / 128, 4, kB), 256, 0, stream>>>(pa);
  }

  // 8) fused reconstruction + transpose
  sfb_fused_kernel<<<dim3(11, kB), 256, 0, stream>>>(P0, P1, P2, P3, outf);
}

// Round 8
// 751.144 us; speedup vs baseline: 1.0401x; 1.0132x over previous
//
#include <hip/hip_runtime.h>
#include <hip/hip_bf16.h>
#include <math.h>

namespace {
constexpr int kB  = 128;
constexpr int kC  = 321;
constexpr int kN0 = 720;
constexpr int kCp = 384;   // padded channel dim for MFMA
}

typedef __attribute__((ext_vector_type(8))) short short8;
typedef __attribute__((ext_vector_type(4))) float floatx4;

// db6 analysis filters (H0 = lowpass, H1 = qmf highpass), and reversed copies
__constant__ float c_h0[12] = {
  0.11154074335008017f, 0.4946238903983854f, 0.7511339080215775f,
  0.3152503517092432f, -0.22626469396516913f, -0.12976686756709563f,
  0.09750160558707936f, 0.02752286553001629f, -0.031582039318031156f,
  0.0005538422009938016f, 0.004777257511010651f, -0.00107730108499558f};
__constant__ float c_h1[12] = {
  -0.00107730108499558f, -0.004777257511010651f, 0.0005538422009938016f,
  0.031582039318031156f, 0.02752286553001629f, -0.09750160558707936f,
  -0.12976686756709563f, 0.22626469396516913f, 0.3152503517092432f,
  -0.7511339080215775f, 0.4946238903983854f, -0.11154074335008017f};
__constant__ float c_h0r[12] = {
  -0.00107730108499558f, 0.004777257511010651f, 0.0005538422009938016f,
  -0.031582039318031156f, 0.02752286553001629f, 0.09750160558707936f,
  -0.12976686756709563f, -0.22626469396516913f, 0.3152503517092432f,
  0.7511339080215775f, 0.4946238903983854f, 0.11154074335008017f};
__constant__ float c_h1r[12] = {
  -0.11154074335008017f, 0.4946238903983854f, -0.7511339080215775f,
  0.3152503517092432f, 0.22626469396516913f, -0.12976686756709563f,
  -0.09750160558707936f, 0.02752286553001629f, 0.031582039318031156f,
  0.0005538422009938016f, -0.004777257511010651f, -0.00107730108499558f};

__device__ __forceinline__ float fast_tanh(float x) {
  float e = __expf(2.f * x);
  return 1.f - 2.f / (e + 1.f);
}
__device__ __forceinline__ unsigned short f2b(float f) {
  __hip_bfloat16 h = __float2bfloat16(f);
  return __builtin_bit_cast(unsigned short, h);
}

// async global->LDS, 16B per lane; LDS dest = wave-uniform base + lane*16
__device__ __forceinline__ void gload16(const unsigned short* g, short* l) {
  __builtin_amdgcn_global_load_lds(
      (const __attribute__((address_space(1))) unsigned int*)g,
      (__attribute__((address_space(3))) unsigned int*)l, 16, 0, 0);
}

// ---------- mean/std over time axis: 8 chunks x 90 t, unrolled for MLP ----------
__global__ void __launch_bounds__(128) partial_ms_kernel(
    const float* __restrict__ x, float* __restrict__ ps, float* __restrict__ ps2) {
  int b = blockIdx.x, chunk = blockIdx.y;
  int c = blockIdx.z * 128 + threadIdx.x;
  if (c >= kC) return;
  const float* xb = x + (size_t)b * kN0 * kC + c;
  int t0 = chunk * 90;
  float s = 0.f, s2 = 0.f;
#pragma unroll 15
  for (int i = 0; i < 90; ++i) {
    float v = xb[(size_t)(t0 + i) * kC];
    s += v; s2 += v * v;
  }
  ps [(b * 8 + chunk) * kC + c] = s;
  ps2[(b * 8 + chunk) * kC + c] = s2;
}

__global__ void __launch_bounds__(256) finalize_ms_kernel(
    const float* __restrict__ ps, const float* __restrict__ ps2,
    float* __restrict__ mout, float* __restrict__ sout,
    float* __restrict__ meanw, float* __restrict__ invw) {
  int i = blockIdx.x * 256 + threadIdx.x;
  if (i >= kB * kC) return;
  int b = i / kC, c = i - b * kC;
  float s = 0.f, s2 = 0.f;
#pragma unroll
  for (int k = 0; k < 8; ++k) { s += ps[(b * 8 + k) * kC + c]; s2 += ps2[(b * 8 + k) * kC + c]; }
  float mean = s * (1.f / (float)kN0);
  float var = s2 * (1.f / (float)kN0) - mean * mean;
  float sd = sqrtf(var + 1e-5f);
  mout[i] = mean; sout[i] = sd;
  meanw[i] = mean; invw[i] = 1.f / sd;
}

__device__ __forceinline__ int sym_reflect(int t, int N) {
  t = (t < 0) ? (-1 - t) : t;
  t = (t >= N) ? (2 * N - 1 - t) : t;
  return t;
}

// ---------- fused tiled DWT level ----------
template <bool NORM, bool LO_F32, bool LO_BF16>
__global__ void __launch_bounds__(256) dwt_fused_kernel(
    const float* __restrict__ in, const float* __restrict__ meanw,
    const float* __restrict__ invw, float* __restrict__ loF,
    unsigned short* __restrict__ loB, unsigned short* __restrict__ hiB,
    int N, int L, int Lp) {
  __shared__ float xs[138][64];
  __shared__ unsigned short los[64][72];
  __shared__ unsigned short his[64][72];
  const int b = blockIdx.z;
  const int n0 = blockIdx.x * 64, c0 = blockIdx.y * 64;
  const int tid = threadIdx.x;
  const int cl = tid & 63, wv = tid >> 6;
  const int c = c0 + cl;
  const int t0 = 2 * n0 - 10;
  const float* ib = in + (size_t)b * N * kC;
  float mean = 0.f, inv = 1.f;
  if (NORM && c < kC) { mean = meanw[b * kC + c]; inv = invw[b * kC + c]; }
  for (int r = wv; r < 138; r += 4) {
    int t = sym_reflect(t0 + r, N);
    float v = (c < kC) ? ib[(size_t)t * kC + c] : 0.f;
    if (NORM) v = (v - mean) * inv;
    xs[r][cl] = v;
  }
  __syncthreads();
#pragma unroll 4
  for (int k = 0; k < 16; ++k) {
    int nl = wv + 4 * k;
    int n = n0 + nl;
    float a0 = 0.f, a1 = 0.f;
    int base = 2 * nl;
#pragma unroll
    for (int j = 0; j < 12; ++j) {
      float v = xs[base + j][cl];
      a0 += v * c_h0[j]; a1 += v * c_h1[j];
    }
    bool valid = (n < L) && (c < kC);
    if (LO_F32 && valid) loF[((size_t)b * L + n) * kC + c] = a0;
    if (LO_BF16) los[cl][nl] = f2b(valid ? a0 : 0.f);
    his[cl][nl] = f2b(valid ? a1 : 0.f);
  }
  __syncthreads();
  int row = tid >> 2, part = tid & 3;
  size_t dst = ((size_t)b * kCp + c0 + row) * Lp + n0 + part * 16;
  *(uint4*)(hiB + dst)     = *(const uint4*)&his[row][part * 16];
  *(uint4*)(hiB + dst + 8) = *(const uint4*)&his[row][part * 16 + 8];
  if (LO_BF16) {
    *(uint4*)(loB + dst)     = *(const uint4*)&los[row][part * 16];
    *(uint4*)(loB + dst + 8) = *(const uint4*)&los[row][part * 16 + 8];
  }
}

// ---------- all-level weight fp32 [L][L] -> bf16 [Lp][Lp] zero-padded ----------
struct WcArgs { const float* src[8]; unsigned short* dst[8]; int L[8]; int Lp[8]; };
__global__ void __launch_bounds__(256) wconv_all_kernel(WcArgs a) {
  int lvl = blockIdx.y;
  int Lp = a.Lp[lvl], L = a.L[lvl];
  int i = blockIdx.x * 256 + threadIdx.x;
  if (i >= Lp * Lp) return;
  int p = i / Lp, l = i - p * Lp;
  a.dst[lvl][i] = f2b((p < L && l < L) ? a.src[lvl][(size_t)p * L + l] : 0.f);
}

// ---------- fully-unrolled K-loop for qk (NT = 4, 6, or 12) ----------
template <int NT>
__device__ __forceinline__ void qk_kloop(
    short* smem, const unsigned short* s0, const unsigned short* s1,
    const unsigned short* s2, bool extra, int lo0, int lo1, int lo2,
    int ar, int bb, floatx4 (&acc)[2][4]) {
  gload16(s0, &smem[lo0]);
  gload16(s1, &smem[lo1]);
  if (extra) gload16(s2, &smem[lo2]);
  __syncthreads();
#pragma unroll
  for (int kt = 0; kt < NT; ++kt) {
    if (kt + 1 < NT) {
      const int phn = ((kt + 1) & 1) * 10240;
      const int go = (kt + 1) * 32;
      gload16(s0 + go, &smem[phn + lo0]);
      gload16(s1 + go, &smem[phn + lo1]);
      if (extra) gload16(s2 + go, &smem[phn + lo2]);
    }
    const int ph = (kt & 1) * 10240;
    short8 aq = *(const short8*)&smem[ph + ar];
    short8 ak = *(const short8*)&smem[ph + 4096 + ar];
    short8 bv[4];
#pragma unroll
    for (int ni = 0; ni < 4; ++ni)
      bv[ni] = *(const short8*)&smem[ph + 8192 + bb + ni * 512];
#pragma unroll
    for (int ni = 0; ni < 4; ++ni) {
      acc[0][ni] = __builtin_amdgcn_mfma_f32_16x16x32_bf16(aq, bv[ni], acc[0][ni], 0, 0, 0);
      acc[1][ni] = __builtin_amdgcn_mfma_f32_16x16x32_bf16(ak, bv[ni], acc[1][ni], 0, 0, 0);
    }
    __syncthreads();
  }
}

// ---------- ALL levels Q+K projections fused, K-step 32, dbuf 40 KB.
// Chunk-XOR swizzle (16B granule, key (row>>1)&3): source inverse-swizzled,
// LDS dest linear (global_load_lds), reads use per-lane constant phys chunk.
// K-loop compile-time unrolled (NT in {4,6,12}); wave-uniform staging roles
// scalarized via readfirstlane. Waves 0-3 stage W0 + X, waves 4-7 stage W1.
// Epilogue: LDS bounce -> uint4 coalesced stores, pad rows (p>=L) skipped. ----------
struct QKAllArgs {
  const unsigned short* W[8];     // [2*lvl+sel]
  const unsigned short* Xt[4];
  const float* bias[8];
  unsigned short* Y[8];
  int Lp[4], L[4], yOff[4];       // yOff = {0,1,4,6} (p-tiles per level: 1,3,2,1)
};
__global__ void __launch_bounds__(512, 8) qk_all_kernel(QKAllArgs a) {
  const int y = blockIdx.y;
  const int lvl = (y >= a.yOff[1]) + (y >= a.yOff[2]) + (y >= a.yOff[3]);
  const int Lp = a.Lp[lvl], L = a.L[lvl];
  const int pBase = (y - a.yOff[lvl]) * 128;
  const unsigned short* W0 = a.W[2 * lvl]     + (size_t)pBase * Lp;
  const unsigned short* W1 = a.W[2 * lvl + 1] + (size_t)pBase * Lp;
  const int b = blockIdx.z;
  const int cBase = blockIdx.x * 64;
  const int tid = threadIdx.x;
  const int ln = tid & 63;
  const int w = __builtin_amdgcn_readfirstlane(tid >> 6);   // SGPR wave id
  __shared__ short smem[2 * 320 * 32];   // 40 KB: 2 phases x (Aq128|Ak128|Bs64) x 32
  floatx4 acc[2][4] = {};                // [out s][ni]
  const unsigned short* Xb = a.Xt[lvl] + ((size_t)b * kCp + cBase) * Lp;
  // staging: octet o covers 16 rows of 64 B; lane -> row o*16+(ln>>2),
  // physical chunk ln&3; source logical chunk = (phys - ((row>>1)&3))&3.
  // waves 0-3: o = {2w, 2w+1, 16+w} (W0 rows + X rows); waves 4-7: o = {2w, 2w+1} (W1).
  const int lr = ln >> 2;
  const int kOfs = ((((ln & 3) - ((ln >> 3) & 3)) & 3)) * 8;   // shorts
  const bool extra = (w < 4);
  const int o0 = 2 * w, o1 = 2 * w + 1;
  const unsigned short* s0 = (extra ? (W0 + (size_t)(o0 * 16 + lr) * Lp)
                                    : (W1 + (size_t)((o0 - 8) * 16 + lr) * Lp)) + kOfs;
  const unsigned short* s1 = (extra ? (W0 + (size_t)(o1 * 16 + lr) * Lp)
                                    : (W1 + (size_t)((o1 - 8) * 16 + lr) * Lp)) + kOfs;
  const unsigned short* s2 = Xb + (size_t)(w * 16 + lr) * Lp + kOfs;
  const int lo0 = o0 * 512, lo1 = o1 * 512, lo2 = (16 + w) * 512;
  // fragment read: physical chunk = ((ln>>4) + ((ln>>1)&3)) & 3
  const int sc = ((((ln >> 4) + ((ln >> 1) & 3)) & 3)) * 8;
  const int ar = (w * 16 + (ln & 15)) * 32 + sc;
  const int bb = (ln & 15) * 32 + sc;
  const int nt = (L + 31) >> 5;          // trimmed: trailing l-chunks are zero
  if (nt == 4)      qk_kloop<4>(smem, s0, s1, s2, extra, lo0, lo1, lo2, ar, bb, acc);
  else if (nt == 6) qk_kloop<6>(smem, s0, s1, s2, extra, lo0, lo1, lo2, ar, bb, acc);
  else              qk_kloop<12>(smem, s0, s1, s2, extra, lo0, lo1, lo2, ar, bb, acc);
  // epilogue via LDS bounce (smem free after final barrier).
  // K needs c<kC zeroing (pad-c kills pad products in scores).
  // Pad rows (p>=L) are NOT stored: scores predicates l<L, masks s<L.
  short* yq = smem;
  short* yk = smem + 8192;
#pragma unroll
  for (int s = 0; s < 2; ++s) {
    const float* bias = a.bias[2 * lvl + s];
    short* dstL = s ? yk : yq;
#pragma unroll
    for (int r = 0; r < 4; ++r) {
      int pl = w * 16 + (ln >> 4) * 4 + r;
      int p = pBase + pl;
      bool pv = (p < L);
      float bvf = pv ? bias[p] : 0.f;
#pragma unroll
      for (int ni = 0; ni < 4; ++ni) {
        int cl = ni * 16 + (ln & 15);
        float v = fast_tanh(acc[s][ni][r] + bvf);
        if (s == 1 && cBase + cl >= kC) v = 0.f;
        dstL[pl * 64 + (cl ^ ((pl & 7) << 3))] = (short)f2b(v);
      }
    }
  }
  __syncthreads();
#pragma unroll
  for (int s = 0; s < 2; ++s) {
    unsigned short* Yd = a.Y[2 * lvl + s];
    const short* srcL = s ? yk : yq;
#pragma unroll
    for (int j = 0; j < 2; ++j) {
      int idx = tid * 2 + j;           // 0..1023
      int row = idx >> 3;              // 0..127
      if (pBase + row >= L) continue;  // skip pad-row stores
      int ch = idx & 7;                // logical 8-short chunk
      int pch = ch ^ (row & 7);        // physical chunk
      uint4 vv = *(const uint4*)&srcL[row * 64 + pch * 8];
      *(uint4*)(Yd + ((size_t)b * Lp + pBase + row) * kCp + cBase + ch * 8) = vv;
    }
  }
}

// ---------- ALL levels scores, K-step 32, dbuf 32 KB, 512 thr.
// 1D grid + bijective XCD swizzle (1920 blocks, 240/XCD). Same chunk-XOR
// swizzle as qk. c-loop is compile-time NT=11 fully unrolled.
// Reduction predicated on l<L (Q pad rows are not written). ----------
struct ScAllArgs {
  const unsigned short* Q[4]; const unsigned short* K[4];
  float* wgt[4];
  int Lp[4], L[4], tOff[4];     // tOff = {0,1,10,14}
  float scale[4];
};
__global__ void __launch_bounds__(512, 8) scores_all_kernel(ScAllArgs a) {
  const int bid = blockIdx.x;                 // 0..1919
  const int wg = (bid & 7) * 240 + (bid >> 3);
  const int t = wg % 15;
  const int b = wg / 15;
  const int lvl = (t >= a.tOff[1]) + (t >= a.tOff[2]) + (t >= a.tOff[3]);
  const int rel = t - a.tOff[lvl];
  const int Lp = a.Lp[lvl], L = a.L[lvl];
  const int pt = Lp >> 7;
  const int sBase = (rel % pt) * 128;
  const int lBase = (rel / pt) * 128;
  const int tid = threadIdx.x;
  const int ln = tid & 63;
  const int w = __builtin_amdgcn_readfirstlane(tid >> 6);
  const int wm = w & 3, wn = w >> 2;     // wave tile 32l x 64s
  __shared__ short smem[2 * 256 * 32];   // 32 KB: 2 phases x (Q128|K128) x 32
  __shared__ float red[128];
  floatx4 acc[2][4] = {};
  const unsigned short* Qp = a.Q[lvl] + ((size_t)b * Lp + lBase) * kCp;
  const unsigned short* Kp = a.K[lvl] + ((size_t)b * Lp + sBase) * kCp;
  const int lr = ln >> 2;
  const int kOfs = ((((ln & 3) - ((ln >> 3) & 3)) & 3)) * 8;
  const int o0 = 2 * w, o1 = 2 * w + 1;
  const unsigned short* s0 = ((o0 < 8) ? (Qp + (size_t)(o0 * 16 + lr) * kCp)
                                       : (Kp + (size_t)((o0 - 8) * 16 + lr) * kCp)) + kOfs;
  const unsigned short* s1 = ((o1 < 8) ? (Qp + (size_t)(o1 * 16 + lr) * kCp)
                                       : (Kp + (size_t)((o1 - 8) * 16 + lr) * kCp)) + kOfs;
  const int lo0 = o0 * 512, lo1 = o1 * 512;
  const int sc = ((((ln >> 4) + ((ln >> 1) & 3)) & 3)) * 8;
  const int aBase = (wm * 32 + (ln & 15)) * 32 + sc;      // +mi*512
  const int bBase = 4096 + (wn * 64 + (ln & 15)) * 32 + sc; // +ni*512
  gload16(s0, &smem[lo0]);
  gload16(s1, &smem[lo1]);
  if (tid < 128) red[tid] = 0.f;
  __syncthreads();
  constexpr int NT = (kC + 31) >> 5;   // 11: c in [352,384) is all-zero K
#pragma unroll
  for (int kt = 0; kt < NT; ++kt) {
    if (kt + 1 < NT) {
      const int phn = ((kt + 1) & 1) * 8192;
      const int go = (kt + 1) * 32;
      gload16(s0 + go, &smem[phn + lo0]);
      gload16(s1 + go, &smem[phn + lo1]);
    }
    const int ph = (kt & 1) * 8192;
    short8 av[2], bv[4];
#pragma unroll
    for (int mi = 0; mi < 2; ++mi)
      av[mi] = *(const short8*)&smem[ph + aBase + mi * 512];
#pragma unroll
    for (int ni = 0; ni < 4; ++ni)
      bv[ni] = *(const short8*)&smem[ph + bBase + ni * 512];
#pragma unroll
    for (int mi = 0; mi < 2; ++mi)
#pragma unroll
      for (int ni = 0; ni < 4; ++ni)
        acc[mi][ni] = __builtin_amdgcn_mfma_f32_16x16x32_bf16(av[mi], bv[ni], acc[mi][ni], 0, 0, 0);
    __syncthreads();
  }
  const float scale = a.scale[lvl];
#pragma unroll
  for (int ni = 0; ni < 4; ++ni) {
    float p = 0.f;
#pragma unroll
    for (int mi = 0; mi < 2; ++mi)
#pragma unroll
      for (int r = 0; r < 4; ++r) {
        int l = lBase + wm * 32 + mi * 16 + (ln >> 4) * 4 + r;
        if (l < L) p += fast_tanh(acc[mi][ni][r] * scale);
      }
    p += __shfl_xor(p, 16);
    p += __shfl_xor(p, 32);
    if ((ln & 48) == 0) atomicAdd(&red[wn * 64 + ni * 16 + (ln & 15)], p);
  }
  __syncthreads();
  if (tid < 128) {
    int s = sBase + tid;
    if (s < L) atomicAdd(&a.wgt[lvl][(size_t)b * L + s], red[tid]);
  }
}

// ---------- merged window mask + iw softmax (one launch) ----------
struct WinIwArgs {
  const float* wgt[4]; const float* al[4]; const float* be[4];
  float* mask[4]; int L[4];
  const float* iw[4]; float* sm[4]; int O[4];
};
__global__ void __launch_bounds__(64) winiw_kernel(WinIwArgs a) {
  int bx = blockIdx.x;
  int lane = threadIdx.x;
  if (bx < 512) {
    int lvl = bx >> 7, b = bx & 127;
    int L = a.L[lvl];
    const float* wgt = a.wgt[lvl] + (size_t)b * L;
    float al = a.al[lvl][0], be = a.be[lvl][0];
    float invL = 1.f / (float)L;
    int chunk = (L + 63) >> 6;            // <= 6
    int s0 = lane * chunk;
    float v[6];
    float csum = 0.f;
    for (int i = chunk - 1; i >= 0; --i) {
      int s = s0 + i;
      float xv = (s < L) ? wgt[s] * invL : 0.f;
      csum += xv; v[i] = csum;
    }
    float tot = csum;
    for (int o = 1; o < 64; o <<= 1) {
      float t = __shfl_down(tot, o);
      if (lane + o < 64) tot += t;
    }
    float excl = tot - csum;
    float m = -1e30f;
    for (int i = 0; i < chunk; ++i)
      if (s0 + i < L) m = fmaxf(m, al * (v[i] + excl));
    for (int o = 32; o; o >>= 1) m = fmaxf(m, __shfl_xor(m, o));
    float sum = 0.f, num = 0.f;
    for (int i = 0; i < chunk; ++i) {
      int s = s0 + i;
      if (s < L) { float e = __expf(al * (v[i] + excl) - m); sum += e; num += e * (float)s; }
    }
    for (int o = 32; o; o >>= 1) { sum += __shfl_xor(sum, o); num += __shfl_xor(num, o); }
    float win = num / sum;
    float* mk = a.mask[lvl] + (size_t)b * L;
    for (int i = 0; i < chunk; ++i) {
      int s = s0 + i;
      if (s < L) mk[s] = 1.f / (1.f + __expf(-((float)s - win) * be));
    }
  } else {
    int x = bx - 512;
    int lvl, o;
    if (x < 22) { lvl = 0; o = x; }
    else if (x < 79) { lvl = 1; o = x - 22; }
    else if (x < 113) { lvl = 2; o = x - 79; }
    else { lvl = 3; o = x - 113; }
    int O = a.O[lvl];
    const float* iw = a.iw[lvl];
    float m = -1e30f;
    for (int c = lane; c < kC; c += 64) m = fmaxf(m, iw[c * O + o]);
    for (int k = 32; k; k >>= 1) m = fmaxf(m, __shfl_xor(m, k));
    float sum = 0.f;
    for (int c = lane; c < kC; c += 64) sum += __expf(iw[c * O + o] - m);
    for (int k = 32; k; k >>= 1) sum += __shfl_xor(sum, k);
    float inv = 1.f / sum;
    for (int c = lane; c < kC; c += 64) a.sm[lvl][c * O + o] = __expf(iw[c * O + o] - m) * inv;
  }
}

// ---------- ALL levels pred via MFMA ----------
struct PredAllArgs {
  const unsigned short* Xt[4];
  const float* PW[4]; const float* PB[4]; const float* MK[4]; const float* SM[4];
  float* OUT[4];
  int L[4], Lp[4], O[4];
};
__global__ void __launch_bounds__(256) pred_all_kernel(PredAllArgs a) {
  const int lvl = blockIdx.y;
  const int L = a.L[lvl], Lp = a.Lp[lvl], O = a.O[lvl];
  const float* PW = a.PW[lvl];
  const int b = blockIdx.z;
  const int cBase = blockIdx.x * 128;
  const int tid = threadIdx.x;
  const int ln = tid & 63, w = tid >> 6;
  __shared__ short As[64 * 40];
  __shared__ short Bs[128 * 40];
  floatx4 acc[8] = {};
  const unsigned short* Xb = a.Xt[lvl] + ((size_t)b * kCp + cBase) * Lp;
  const float* mk = a.MK[lvl] + (size_t)b * L;
  for (int lc = 0; lc < Lp; lc += 32) {
    {
      int o = tid >> 2, j0 = (tid & 3) * 8;
      alignas(16) unsigned short tmp[8];
#pragma unroll
      for (int j = 0; j < 8; ++j) {
        int l = lc + j0 + j;
        float v = (o < O && l < L) ? PW[(size_t)o * L + l] * mk[l] : 0.f;
        tmp[j] = f2b(v);
      }
      *(uint4*)&As[o * 40 + j0] = *(const uint4*)tmp;
    }
#pragma unroll
    for (int q = 0; q < 2; ++q) {
      int ch = tid * 2 + q;
      int row = ch >> 2, pos = ch & 3;
      *(uint4*)(&Bs[row * 40 + pos * 8]) = *(const uint4*)(Xb + (size_t)row * Lp + lc + pos * 8);
    }
    __syncthreads();
    short8 av = *(const short8*)&As[(w * 16 + (ln & 15)) * 40 + (ln >> 4) * 8];
#pragma unroll
    for (int ni = 0; ni < 8; ++ni) {
      short8 bb = *(const short8*)&Bs[(ni * 16 + (ln & 15)) * 40 + (ln >> 4) * 8];
      acc[ni] = __builtin_amdgcn_mfma_f32_16x16x32_bf16(av, bb, acc[ni], 0, 0, 0);
    }
    __syncthreads();
  }
  const float negln = -logf(10000.f) / (float)O;
#pragma unroll
  for (int ni = 0; ni < 8; ++ni) {
    int c = cBase + ni * 16 + (ln & 15);
    if (c >= kC) continue;
#pragma unroll
    for (int r = 0; r < 4; ++r) {
      int o = w * 16 + (ln >> 4) * 4 + r;
      if (o >= O) continue;
      float dv = __expf(negln * (float)(2 * (o >> 1)));
      float ang = (float)c * dv;
      float pe = (o & 1) ? cosf(ang) : sinf(ang);
      a.OUT[lvl][((size_t)b * O + o) * kC + c] = a.SM[lvl][c * O + o] * (acc[ni][r] + a.PB[lvl][o] + pe);
    }
  }
}

// ---------- fused 3-stage synthesis + transpose: out[b][c][104] ----------
__global__ void __launch_bounds__(256) sfb_fused_kernel(
    const float* __restrict__ P0, const float* __restrict__ P1,
    const float* __restrict__ P2, const float* __restrict__ P3,
    float* __restrict__ out) {
  __shared__ float p0s[22][32], p3s[22][32], p2s[34][32], p1s[57][32];
  __shared__ float r1s[34][32], r2s[58][32];
  __shared__ float outs[104][33];
  int b = blockIdx.y, c0 = blockIdx.x * 32;
  int tid = threadIdx.x;
  int cl = tid & 31, r = tid >> 5;
  int c = c0 + cl;
  bool cv = c < kC;
  for (int o = r; o < 22; o += 8) {
    p0s[o][cl] = cv ? P0[((size_t)b * 22 + o) * kC + c] : 0.f;
    p3s[o][cl] = cv ? P3[((size_t)b * 22 + o) * kC + c] : 0.f;
  }
  for (int o = r; o < 34; o += 8) p2s[o][cl] = cv ? P2[((size_t)b * 34 + o) * kC + c] : 0.f;
  for (int o = r; o < 57; o += 8) p1s[o][cl] = cv ? P1[((size_t)b * 57 + o) * kC + c] : 0.f;
  __syncthreads();
  for (int n = r; n < 34; n += 8) {
    float acc = 0.f;
#pragma unroll
    for (int j = 0; j < 12; ++j) {
      int m = n + j - 1;
      if (m < 0 || (m & 1)) continue;
      int i = m >> 1;
      if (i >= 22) continue;
      acc += c_h0r[j] * p0s[i][cl] + c_h1r[j] * p3s[i][cl];
    }
    r1s[n][cl] = acc;
  }
  __syncthreads();
  for (int n = r; n < 58; n += 8) {
    float acc = 0.f;
#pragma unroll
    for (int j = 0; j < 12; ++j) {
      int m = n + j - 1;
      if (m < 0 || (m & 1)) continue;
      int i = m >> 1;
      if (i >= 34) continue;
      acc += c_h0r[j] * r1s[i][cl] + c_h1r[j] * p2s[i][cl];
    }
    r2s[n][cl] = acc;
  }
  __syncthreads();
  for (int n = r; n < 104; n += 8) {
    float acc = 0.f;
#pragma unroll
    for (int j = 0; j < 12; ++j) {
      int m = n + j - 1;
      if (m < 0 || (m & 1)) continue;
      int i = m >> 1;
      if (i >= 57) continue;
      acc += c_h0r[j] * r2s[i][cl] + c_h1r[j] * p1s[i][cl];
    }
    outs[n][cl] = acc;
  }
  __syncthreads();
  for (int idx = tid; idx < 32 * 104; idx += 256) {
    int ci = idx / 104, n = idx - ci * 104;
    int cg = c0 + ci;
    if (cg < kC) out[((size_t)b * kC + cg) * 104 + n] = outs[n][ci];
  }
}

extern "C" void kernel_launch(void* const* d_in, const int* in_sizes, int n_in,
                              void* d_out, int out_size, void* d_ws, size_t ws_size,
                              hipStream_t stream) {
  (void)in_sizes; (void)n_in; (void)out_size; (void)ws_size;
  const float* x = (const float*)d_in[0];
  auto inp = [&](int lvl, int j) { return (const float*)d_in[1 + 9 * lvl + j]; };

  float* outf = (float*)d_out;
  float* mout = outf + (size_t)kB * kC * 104;
  float* sout = mout + (size_t)kB * kC;

  float* Wp = (float*)d_ws;
  size_t off = 0;
  auto alloc = [&](size_t n) { float* p = Wp + off; off += (n + 63) & ~(size_t)63; return p; };

  // LO1+LO2 first & contiguous: later aliased as concatenated Q bf16 buffer (91 MB >= 88.1 MB)
  float* LO1 = alloc((size_t)kB * 365 * kC);
  float* LO2 = alloc((size_t)kB * 188 * kC);
  unsigned short* Xt1 = (unsigned short*)alloc((size_t)kB * kCp * 384 / 2);
  unsigned short* Xt2 = (unsigned short*)alloc((size_t)kB * kCp * 256 / 2);
  unsigned short* Xt0 = (unsigned short*)alloc((size_t)kB * kCp * 128 / 2);
  unsigned short* Xt3 = (unsigned short*)alloc((size_t)kB * kCp * 128 / 2);
  unsigned short* KbfAll = (unsigned short*)alloc((size_t)kB * kCp * 896 / 2);
  unsigned short* Wpv[8];
  for (int i = 0; i < 8; ++i)
    Wpv[i] = (unsigned short*)alloc((size_t)384 * 384 / 2);
  float* wgtAll = alloc((size_t)kB * (99 + 365 + 188 + 99));
  float* M0 = alloc((size_t)kB * 99);  float* M1 = alloc((size_t)kB * 365);
  float* M2 = alloc((size_t)kB * 188); float* M3 = alloc((size_t)kB * 99);
  float* S0 = alloc((size_t)kC * 22);  float* S1 = alloc((size_t)kC * 57);
  float* S2 = alloc((size_t)kC * 34);  float* S3 = alloc((size_t)kC * 22);
  float* P0 = alloc((size_t)kB * 22 * kC); float* P1 = alloc((size_t)kB * 57 * kC);
  float* P2 = alloc((size_t)kB * 34 * kC); float* P3 = alloc((size_t)kB * 22 * kC);
  float* ps   = alloc((size_t)kB * 8 * kC);
  float* ps2  = alloc((size_t)kB * 8 * kC);
  float* meanw = alloc((size_t)kB * kC);
  float* invw  = alloc((size_t)kB * kC);
  unsigned short* QbfAll = (unsigned short*)LO1;   // alias over LO1+LO2 (dead before qk_all)

  const int Lc[4]  = {99, 365, 188, 99};
  const int Lpv[4] = {128, 384, 256, 128};
  const int Ov[4]  = {22, 57, 34, 22};
  const int prefLp[4] = {0, 128, 512, 768};
  const int wOff[4] = {0, 99, 99 + 365, 99 + 365 + 188};
  unsigned short* Qlvl[4]; unsigned short* Klvl[4];
  for (int i = 0; i < 4; ++i) {
    Qlvl[i] = QbfAll + (size_t)kB * kCp * prefLp[i];
    Klvl[i] = KbfAll + (size_t)kB * kCp * prefLp[i];
  }
  const unsigned short* Xts[4] = {Xt0, Xt1, Xt2, Xt3};
  float* masks[4] = {M0, M1, M2, M3};
  float* smws[4]  = {S0, S1, S2, S3};
  float* preds[4] = {P0, P1, P2, P3};

  // 1) mean/std
  partial_ms_kernel<<<dim3(kB, 8, 3), 128, 0, stream>>>(x, ps, ps2);
  finalize_ms_kernel<<<(kB * kC + 255) / 256, 256, 0, stream>>>(ps, ps2, mout, sout, meanw, invw);

  // 2) fused DWT cascade
  dwt_fused_kernel<true, true, false><<<dim3(6, kCp / 64, kB), 256, 0, stream>>>(
      x, meanw, invw, LO1, nullptr, Xt1, kN0, 365, 384);
  dwt_fused_kernel<false, true, false><<<dim3(4, kCp / 64, kB), 256, 0, stream>>>(
      LO1, nullptr, nullptr, LO2, nullptr, Xt2, 365, 188, 256);
  dwt_fused_kernel<false, false, true><<<dim3(2, kCp / 64, kB), 256, 0, stream>>>(
      LO2, nullptr, nullptr, nullptr, Xt0, Xt3, 188, 99, 128);

  // 3) weight conversions (one launch) + wgt zero
  {
    WcArgs wa;
    for (int i = 0; i < 4; ++i) {
      wa.src[2 * i] = inp(i, 0); wa.src[2 * i + 1] = inp(i, 2);
      wa.dst[2 * i] = Wpv[2 * i]; wa.dst[2 * i + 1] = Wpv[2 * i + 1];
      wa.L[2 * i] = wa.L[2 * i + 1] = Lc[i];
      wa.Lp[2 * i] = wa.Lp[2 * i + 1] = Lpv[i];
    }
    wconv_all_kernel<<<dim3(576, 8), 256, 0, stream>>>(wa);
  }
  hipMemsetAsync(wgtAll, 0, (size_t)kB * (99 + 365 + 188 + 99) * sizeof(float), stream);

  // 4) all-level fused Q+K projections (one launch; runs after dwt3 so LO1/LO2 alias is safe)
  {
    QKAllArgs qa;
    for (int i = 0; i < 4; ++i) {
      qa.W[2 * i] = Wpv[2 * i]; qa.W[2 * i + 1] = Wpv[2 * i + 1];
      qa.bias[2 * i] = inp(i, 1); qa.bias[2 * i + 1] = inp(i, 3);
      qa.Y[2 * i] = Qlvl[i]; qa.Y[2 * i + 1] = Klvl[i];
      qa.Xt[i] = Xts[i]; qa.Lp[i] = Lpv[i]; qa.L[i] = Lc[i];
    }
    qa.yOff[0] = 0; qa.yOff[1] = 1; qa.yOff[2] = 4; qa.yOff[3] = 6;  // p-tiles: 1,3,2,1
    qk_all_kernel<<<dim3(kCp / 64, 7, kB), 512, 0, stream>>>(qa);
  }

  // 5) all-level scores (one launch, 1D grid + XCD swizzle)
  {
    ScAllArgs sa;
    for (int i = 0; i < 4; ++i) {
      sa.Q[i] = Qlvl[i]; sa.K[i] = Klvl[i];
      sa.wgt[i] = wgtAll + (size_t)kB * wOff[i];
      sa.Lp[i] = Lpv[i]; sa.L[i] = Lc[i];
      sa.scale[i] = 1.0f / sqrtf((float)Lc[i]);
    }
    sa.tOff[0] = 0; sa.tOff[1] = 1; sa.tOff[2] = 10; sa.tOff[3] = 14;  // 1,9,4,1 tiles
    scores_all_kernel<<<15 * kB, 512, 0, stream>>>(sa);
  }

  // 6) window masks + channel softmax (merged)
  {
    WinIwArgs wa;
    for (int i = 0; i < 4; ++i) {
      wa.wgt[i] = wgtAll + (size_t)kB * wOff[i];
      wa.al[i] = inp(i, 7); wa.be[i] = inp(i, 8);
      wa.mask[i] = masks[i]; wa.L[i] = Lc[i];
      wa.iw[i] = inp(i, 6); wa.sm[i] = smws[i]; wa.O[i] = Ov[i];
    }
    winiw_kernel<<<512 + 135, 64, 0, stream>>>(wa);
  }

  // 7) all-level pred projections (one launch)
  {
    PredAllArgs pa;
    for (int i = 0; i < 4; ++i) {
      pa.Xt[i] = Xts[i]; pa.PW[i] = inp(i, 4); pa.PB[i] = inp(i, 5);
      pa.MK[i] = masks[i]; pa.SM[i] = smws[i]; pa.OUT[i] = preds[i];
      pa.L[i] = Lc[i]; pa.Lp[i] = Lpv[i]; pa.O[i] = Ov[i];
    }
    pred_all_kernel<<<dim3(kCp / 128, 4, kB), 256, 0, stream>>>(pa);
  }

  // 8) fused reconstruction + transpose
  sfb_fused_kernel<<<dim3(11, kB), 256, 0, stream>>>(P0, P1, P2, P3, outf);
}